// Round 15
// baseline (609.043 us; speedup 1.0000x reference)
//
#include <hip/hip_runtime.h>

#define NN 100000
#define EE 1600000
#define BB 64
#define NSCAN 98      // ceil(NN/1024)
#define AG6 1024      // grid for F=6 stats
#define AG64 640      // grid for F=64 tiled ata
#define NTILE 1563    // ceil(NN/64)
#define POOL_BLK 512
#define POOL_WAVES (POOL_BLK * 4)
#define HCLS 8        // hist classes (XCD-private count slices)

typedef float f32x4 __attribute__((ext_vector_type(4)));
typedef short short8 __attribute__((ext_vector_type(8)));

__device__ __forceinline__ unsigned fmap(float f) {
  unsigned u = __float_as_uint(f);
  return (u & 0x80000000u) ? ~u : (u | 0x80000000u);
}
__device__ __forceinline__ float funmap(unsigned m) {
  unsigned u = (m & 0x80000000u) ? (m ^ 0x80000000u) : ~m;
  return __uint_as_float(u);
}
__device__ __forceinline__ unsigned short f2b(float f) {
  unsigned u = __float_as_uint(f);
  unsigned r = (u + 0x7FFFu + ((u >> 16) & 1u)) >> 16;
  return (unsigned short)r;
}
__device__ __forceinline__ float b2f(unsigned short s) {
  return __uint_as_float(((unsigned)s) << 16);
}

// ---------------- CSR build (by dst) ----------------
__global__ void k_hist8(const int* __restrict__ dst, int* __restrict__ counts8,
                        int* __restrict__ rank) {
  int i = blockIdx.x * blockDim.x + threadIdx.x;
  int c = blockIdx.x & (HCLS - 1);
  if (i < EE) rank[i] = atomicAdd(&counts8[c * NN + dst[i]], 1);
}

__global__ void k_off8(int* __restrict__ counts8, int* __restrict__ counts) {
  int n = blockIdx.x * blockDim.x + threadIdx.x;
  if (n >= NN) return;
  int t = 0;
#pragma unroll
  for (int c = 0; c < HCLS; ++c) {
    int v = counts8[c * NN + n];
    counts8[c * NN + n] = t;
    t += v;
  }
  counts[n] = t;
}

__global__ void k_scan1(const int* __restrict__ counts, int* __restrict__ rowptr,
                        int* __restrict__ partials) {
  __shared__ int buf[1024];
  int i = blockIdx.x * 1024 + threadIdx.x;
  int v = (i < NN) ? counts[i] : 0;
  buf[threadIdx.x] = v;
  __syncthreads();
  for (int off = 1; off < 1024; off <<= 1) {
    int t = (threadIdx.x >= off) ? buf[threadIdx.x - off] : 0;
    __syncthreads();
    buf[threadIdx.x] += t;
    __syncthreads();
  }
  int incl = buf[threadIdx.x];
  if (i < NN) rowptr[i] = incl - v;
  if (threadIdx.x == 1023) partials[blockIdx.x] = incl;
}

__global__ void k_scan2(const int* __restrict__ partials, int* __restrict__ poffs,
                        unsigned* __restrict__ gmax) {
  __shared__ int buf[128];
  int t = threadIdx.x;
  int v = (t < NSCAN) ? partials[t] : 0;
  buf[t] = v;
  __syncthreads();
  for (int off = 1; off < 128; off <<= 1) {
    int u = (t >= off) ? buf[t - off] : 0;
    __syncthreads();
    buf[t] += u;
    __syncthreads();
  }
  poffs[t] = buf[t] - v;
  for (int i = t; i < BB * 64; i += 128) gmax[i] = 0x007FFFFFu;  // fmap(-inf)
}

__global__ void k_scan3(int* __restrict__ rowptr, const int* __restrict__ poffs) {
  int i = blockIdx.x * 1024 + threadIdx.x;
  if (i < NN) rowptr[i] += poffs[blockIdx.x];
  if (i == 0) rowptr[NN] = EE;
}

__global__ __launch_bounds__(256) void k_place(const int* __restrict__ src,
                                               const int* __restrict__ dst,
                                               const int* __restrict__ rank,
                                               const int* __restrict__ rowptr,
                                               const int* __restrict__ counts8,
                                               int* __restrict__ adjsrc) {
  int i = blockIdx.x * blockDim.x + threadIdx.x;
  if (i < EE) {
    int c = (i >> 8) & (HCLS - 1);
    int d = dst[i];
    adjsrc[rowptr[d] + counts8[c * NN + d] + rank[i]] = src[i];
  }
}

// ---------------- layer-0 aggregation: f32 gather, F=6 ----------------
__global__ __launch_bounds__(256) void k_agg0(const float* __restrict__ xin,
                                              const int* __restrict__ rowptr,
                                              const int* __restrict__ adjsrc,
                                              float* __restrict__ out) {
  int w = __builtin_amdgcn_readfirstlane(threadIdx.x >> 6);
  int lane = threadIdx.x & 63;
  int wid = blockIdx.x * 4 + w;
  if (wid >= NN) return;
  int s = rowptr[wid], e = rowptr[wid + 1];
  bool act = lane < 6;
  float den = 0.f, num = 0.f;
  int i = s;
  for (; i + 3 < e; i += 4) {
    int n0 = adjsrc[i], n1 = adjsrc[i + 1], n2 = adjsrc[i + 2], n3 = adjsrc[i + 3];
    float v0 = act ? xin[(size_t)n0 * 6 + lane] : 0.f;
    float v1 = act ? xin[(size_t)n1 * 6 + lane] : 0.f;
    float v2 = act ? xin[(size_t)n2 * 6 + lane] : 0.f;
    float v3 = act ? xin[(size_t)n3 * 6 + lane] : 0.f;
    float m0 = fminf(fmaxf(v0, 0.f) + 1e-7f, 80.f);
    float m1 = fminf(fmaxf(v1, 0.f) + 1e-7f, 80.f);
    float m2 = fminf(fmaxf(v2, 0.f) + 1e-7f, 80.f);
    float m3 = fminf(fmaxf(v3, 0.f) + 1e-7f, 80.f);
    float e0 = __expf(m0), e1 = __expf(m1), e2 = __expf(m2), e3 = __expf(m3);
    den += (e0 + e1) + (e2 + e3);
    num += (m0 * e0 + m1 * e1) + (m2 * e2 + m3 * e3);
  }
  for (; i < e; ++i) {
    int n0 = adjsrc[i];
    float v0 = act ? xin[(size_t)n0 * 6 + lane] : 0.f;
    float m0 = fminf(fmaxf(v0, 0.f) + 1e-7f, 80.f);
    float e0 = __expf(m0);
    den += e0;
    num += m0 * e0;
  }
  if (act) {
    float xr = xin[(size_t)wid * 6 + lane];
    out[(size_t)wid * 6 + lane] = num / (den + 1e-16f) + xr;
  }
}

// ---------------- layers 1-3 aggregation: 8-edges-per-gather uint4 bf16 --------
// lane = (eslot<<3)|cgrp: edge-slot eslot handles channel-group cgrp (8 ch/uint4).
// One gather instruction fetches 8 full rows (1KB); 2 batches issued -> 2KB in flight.
__global__ __launch_bounds__(256) void k_aggb(const uint4* __restrict__ xb4,
                                              const float* __restrict__ h,
                                              const int* __restrict__ rowptr,
                                              const int* __restrict__ adjsrc,
                                              float* __restrict__ out) {
  int w = __builtin_amdgcn_readfirstlane(threadIdx.x >> 6);
  int wid = blockIdx.x * 4 + w;
  if (wid >= NN) return;
  int lane = threadIdx.x & 63;
  int eslot = lane >> 3;   // 0..7
  int cgrp = lane & 7;     // channels 8*cgrp .. 8*cgrp+7
  int s = rowptr[wid], e = rowptr[wid + 1];
  float den[8], num[8];
#pragma unroll
  for (int j = 0; j < 8; ++j) { den[j] = 0.f; num[j] = 0.f; }
  for (int base = s; base < e; base += 16) {
    int ei0 = base + eslot;
    int ei1 = base + 8 + eslot;
    bool v0 = ei0 < e, v1 = ei1 < e;
    int n0 = adjsrc[v0 ? ei0 : e - 1];
    int n1 = adjsrc[v1 ? ei1 : e - 1];
    uint4 u0 = xb4[(size_t)n0 * 8 + cgrp];
    uint4 u1 = xb4[(size_t)n1 * 8 + cgrp];
    unsigned uu0[4] = {u0.x, u0.y, u0.z, u0.w};
    unsigned uu1[4] = {u1.x, u1.y, u1.z, u1.w};
#pragma unroll
    for (int p = 0; p < 4; ++p) {
      float alo = __uint_as_float(uu0[p] << 16);
      float ahi = __uint_as_float(uu0[p] & 0xffff0000u);
      float mlo = fminf(alo + 1e-7f, 80.f);
      float mhi = fminf(ahi + 1e-7f, 80.f);
      float elo = v0 ? __expf(mlo) : 0.f;
      float ehi = v0 ? __expf(mhi) : 0.f;
      den[2 * p] += elo;     num[2 * p] += mlo * elo;
      den[2 * p + 1] += ehi; num[2 * p + 1] += mhi * ehi;
      float blo = __uint_as_float(uu1[p] << 16);
      float bhi = __uint_as_float(uu1[p] & 0xffff0000u);
      float nlo = fminf(blo + 1e-7f, 80.f);
      float nhi = fminf(bhi + 1e-7f, 80.f);
      float flo = v1 ? __expf(nlo) : 0.f;
      float fhi = v1 ? __expf(nhi) : 0.f;
      den[2 * p] += flo;     num[2 * p] += nlo * flo;
      den[2 * p + 1] += fhi; num[2 * p + 1] += nhi * fhi;
    }
  }
  // reduce across edge-slots (lane bits 3..5)
#pragma unroll
  for (int j = 0; j < 8; ++j) {
    den[j] += __shfl_xor(den[j], 8, 64);
    num[j] += __shfl_xor(num[j], 8, 64);
    den[j] += __shfl_xor(den[j], 16, 64);
    num[j] += __shfl_xor(num[j], 16, 64);
    den[j] += __shfl_xor(den[j], 32, 64);
    num[j] += __shfl_xor(num[j], 32, 64);
  }
  if (eslot == 0) {
    float o[8];
#pragma unroll
    for (int j = 0; j < 8; ++j) {
      float res = fmaxf(h[(size_t)wid * 64 + 8 * cgrp + j], 0.f);
      o[j] = num[j] / (den[j] + 1e-16f) + res;
    }
    *(float4*)&out[(size_t)wid * 64 + 8 * cgrp] = make_float4(o[0], o[1], o[2], o[3]);
    *(float4*)&out[(size_t)wid * 64 + 8 * cgrp + 4] = make_float4(o[4], o[5], o[6], o[7]);
  }
}

// ---------------- F=6 stats: shfl outer product (cheap) ----------------
__global__ __launch_bounds__(256) void k_ata6(const float* __restrict__ A,
                                              float* __restrict__ part) {
  constexpr int F = 6;
  int lane = threadIdx.x & 63;
  int w = __builtin_amdgcn_readfirstlane(threadIdx.x >> 6);
  bool act = lane < F;
  float Sloc[F];
#pragma unroll
  for (int c = 0; c < F; ++c) Sloc[c] = 0.f;
  float csloc = 0.f;
  int NW = gridDim.x * 4;
  for (int node = blockIdx.x * 4 + w; node < NN; node += NW) {
    float a = act ? A[(size_t)node * F + lane] : 0.f;
    csloc += a;
#pragma unroll
    for (int c = 0; c < F; ++c) {
      float ac = __shfl(a, c, 64);
      Sloc[c] += ac * a;
    }
  }
  __shared__ float ls[F * F + F];
  for (int idx = threadIdx.x; idx < F * F + F; idx += 256) ls[idx] = 0.f;
  __syncthreads();
  if (act) {
#pragma unroll
    for (int c = 0; c < F; ++c) atomicAdd(&ls[c * F + lane], Sloc[c]);
    atomicAdd(&ls[F * F + lane], csloc);
  }
  __syncthreads();
  float* dstp = part + (size_t)blockIdx.x * (F * F + F);
  for (int idx = threadIdx.x; idx < F * F + F; idx += 256) dstp[idx] = ls[idx];
}

// ---------------- F=64 stats: LDS-tiled rank-1 accumulation ----------------
__global__ __launch_bounds__(256) void k_ata64(const float* __restrict__ A,
                                               float* __restrict__ part) {
  __shared__ float lA[64 * 64];   // [node][ch]
  __shared__ float lcs[64];
  int tid = threadIdx.x;
  int tx = tid & 15, ty = tid >> 4;
  float acc[4][4];
#pragma unroll
  for (int i = 0; i < 4; ++i)
#pragma unroll
    for (int j = 0; j < 4; ++j) acc[i][j] = 0.f;
  float cs0 = 0.f, cs1 = 0.f, cs2 = 0.f, cs3 = 0.f;
  if (tid < 64) lcs[tid] = 0.f;
  const float4* A4 = (const float4*)A;
  for (int tile = blockIdx.x; tile < NTILE; tile += gridDim.x) {
    int nbase = tile * 64;
    __syncthreads();   // protect lA from previous iteration's readers
#pragma unroll
    for (int k = 0; k < 4; ++k) {
      int node = ty + k * 16;
      int gn = nbase + node;
      float4 v = (gn < NN) ? A4[(size_t)gn * 16 + tx]
                           : make_float4(0.f, 0.f, 0.f, 0.f);
      *(float4*)&lA[node * 64 + tx * 4] = v;
      cs0 += v.x; cs1 += v.y; cs2 += v.z; cs3 += v.w;
    }
    __syncthreads();
#pragma unroll 4
    for (int node = 0; node < 64; ++node) {
      float4 rv = *(const float4*)&lA[node * 64 + ty * 4];
      float4 cv = *(const float4*)&lA[node * 64 + tx * 4];
      acc[0][0] += rv.x * cv.x; acc[0][1] += rv.x * cv.y;
      acc[0][2] += rv.x * cv.z; acc[0][3] += rv.x * cv.w;
      acc[1][0] += rv.y * cv.x; acc[1][1] += rv.y * cv.y;
      acc[1][2] += rv.y * cv.z; acc[1][3] += rv.y * cv.w;
      acc[2][0] += rv.z * cv.x; acc[2][1] += rv.z * cv.y;
      acc[2][2] += rv.z * cv.z; acc[2][3] += rv.z * cv.w;
      acc[3][0] += rv.w * cv.x; acc[3][1] += rv.w * cv.y;
      acc[3][2] += rv.w * cv.z; acc[3][3] += rv.w * cv.w;
    }
  }
  __syncthreads();
  atomicAdd(&lcs[tx * 4 + 0], cs0);
  atomicAdd(&lcs[tx * 4 + 1], cs1);
  atomicAdd(&lcs[tx * 4 + 2], cs2);
  atomicAdd(&lcs[tx * 4 + 3], cs3);
  float* dstp = part + (size_t)blockIdx.x * 4160;
#pragma unroll
  for (int i = 0; i < 4; ++i)
#pragma unroll
    for (int j = 0; j < 4; ++j)
      dstp[(ty * 4 + i) * 64 + tx * 4 + j] = acc[i][j];
  __syncthreads();
  if (tid < 64) dstp[4096 + tid] = lcs[tid];
}

// ---------------- reduce partials: block-per-index tree ----------------
__global__ void k_redB(const float* __restrict__ part, float* __restrict__ out,
                       int stride, int ngrid) {
  __shared__ float buf[256];
  int i = blockIdx.x;
  float s = 0.f;
  for (int g = threadIdx.x; g < ngrid; g += 256) s += part[(size_t)g * stride + i];
  buf[threadIdx.x] = s;
  __syncthreads();
  for (int off = 128; off; off >>= 1) {
    if (threadIdx.x < off) buf[threadIdx.x] += buf[threadIdx.x + off];
    __syncthreads();
  }
  if (threadIdx.x == 0) out[i] = buf[0];
}

// ---------------- BN params from covariance ----------------
template<int FIN, int FMID>
__global__ void k_bnprep(const float* __restrict__ S, const float* __restrict__ cs,
                         const float* __restrict__ Wm, const float* __restrict__ bm,
                         const float* __restrict__ gamma, const float* __restrict__ beta,
                         float* __restrict__ ab) {
  int j = blockIdx.x;
  int lane = threadIdx.x;
  bool act = (FIN == 64) || (lane < FIN);
  float wj = act ? Wm[lane * FMID + j] : 0.f;
  float mb = act ? cs[lane] * (1.f / NN) : 0.f;
  float t = mb * wj;
#pragma unroll
  for (int off = 32; off; off >>= 1) t += __shfl_xor(t, off, 64);
  float mulin = t;
  float acc = 0.f;
  for (int c = 0; c < FIN; ++c) {
    float sv = act ? S[c * FIN + lane] : 0.f;
    float p = sv * wj;
#pragma unroll
    for (int off = 32; off; off >>= 1) p += __shfl_xor(p, off, 64);
    acc += p * __shfl(wj, c, 64);
  }
  if (lane == 0) {
    float var = acc * (1.f / NN) - mulin * mulin;
    float rstd = rsqrtf(fmaxf(var, 0.f) + 1e-5f);
    float sc = rstd * gamma[j];
    ab[j] = sc;
    ab[FMID + j] = beta[j] - mulin * sc;
  }
}

// ---------------- layer-0 fused GEMM (VALU path, FIN=6) ----------------
template<int FIN, int FMID, int FOUT>
__global__ __launch_bounds__(256) void k_layer(const float* __restrict__ A,
                                               const float* __restrict__ Wm,
                                               const float* __restrict__ ab,
                                               const float* __restrict__ W2,
                                               const float* __restrict__ b2,
                                               float* __restrict__ H,
                                               unsigned short* __restrict__ XB) {
  constexpr int SM = FMID + 1;
  constexpr int MW = FMID / 4;
  constexpr int OW = FOUT / 4;
  __shared__ float lA[FIN * 65];
  __shared__ float lH_sep[64 * SM];
  int tid = threadIdx.x;
  int lane = tid & 63;
  int w = __builtin_amdgcn_readfirstlane(tid >> 6);
  int nbase = blockIdx.x * 64;
  for (int e = tid; e < 64 * FIN; e += 256) {
    int node = e / FIN, c = e - node * FIN;
    int gn = nbase + node;
    lA[c * 65 + node] = (gn < NN) ? A[(size_t)gn * FIN + c] : 0.f;
  }
  __syncthreads();
  float acc[MW];
#pragma unroll
  for (int j = 0; j < MW; ++j) acc[j] = 0.f;
#pragma unroll 4
  for (int c = 0; c < FIN; ++c) {
    float a = lA[c * 65 + lane];
#pragma unroll
    for (int j = 0; j < MW; ++j) acc[j] += a * Wm[c * FMID + w * MW + j];
  }
#pragma unroll
  for (int j = 0; j < MW; ++j) {
    float sc = ab[w * MW + j];
    float sh = ab[FMID + w * MW + j];
    lH_sep[lane * SM + w * MW + j] = fmaxf(acc[j] * sc + sh, 0.f);
  }
  __syncthreads();
  float acc2[OW];
#pragma unroll
  for (int j = 0; j < OW; ++j) acc2[j] = b2[w * OW + j];
#pragma unroll 4
  for (int c = 0; c < FMID; ++c) {
    float hv = lH_sep[lane * SM + c];
#pragma unroll
    for (int j = 0; j < OW; ++j) acc2[j] += hv * W2[c * FOUT + w * OW + j];
  }
  int node = nbase + lane;
  if (node < NN) {
    size_t base = (size_t)node * FOUT + w * OW;
#pragma unroll
    for (int j = 0; j < OW; ++j) {
      float hn = fmaxf(acc2[j], 0.f);
      H[base + j] = hn;
      XB[base + j] = f2b(hn);
    }
  }
}

// ---------------- weight pre-pack to MFMA fragment order (bf16) ----------------
__global__ void k_packW(const float* __restrict__ L_w1, const float* __restrict__ L_w2,
                        short* __restrict__ wmf, short* __restrict__ w2f) {
  int idx = blockIdx.x * 256 + threadIdx.x;
  if (idx >= 3 * 16384) return;
  int layer = idx / 16384;
  int r = idx - layer * 16384;
  bool isW2 = r >= 8192;
  int e = isW2 ? r - 8192 : r;
  int j = e & 7, lane = (e >> 3) & 63, t = e >> 9;
  int kgrp = lane >> 4, nlow = lane & 15;
  if (!isW2) {
    int nt = t >> 1, kc = t & 1;
    int k = kc * 32 + 8 * kgrp + j, n = nt * 16 + nlow;
    wmf[(size_t)layer * 8192 + e] = (short)f2b(L_w1[(size_t)layer * 64 * 128 + k * 128 + n]);
  } else {
    int nt = t >> 2, kc = t & 3;
    int k = kc * 32 + 8 * kgrp + j, n = nt * 16 + nlow;
    w2f[(size_t)layer * 8192 + e] = (short)f2b(L_w2[(size_t)layer * 128 * 64 + k * 64 + n]);
  }
}

// ---------------- MFMA fused layer (layers 1-3) ----------------
__global__ __launch_bounds__(256) void k_layerM(const float* __restrict__ A,
                                                const short* __restrict__ Wmf,
                                                const float* __restrict__ ab,
                                                const short* __restrict__ W2f,
                                                const float* __restrict__ b2,
                                                float* __restrict__ H,
                                                unsigned short* __restrict__ XB) {
  __shared__ short lFrag[8192];   // 16KB; GEMM1 a-frags then GEMM2 a-frags
  __shared__ float ls_ab[256];
  int tid = threadIdx.x;
  int lane = tid & 63;
  int w = tid >> 6;
  int nbase = blockIdx.x * 64;
  ls_ab[tid] = ab[tid];
#pragma unroll
  for (int it = 0; it < 2; ++it) {
    int e = tid + 256 * it;
    int ln = e & 63;
    int m = (e >> 6) & 3;
    int kc = e >> 8;
    int row = nbase + 16 * m + (ln & 15);
    int k0 = 32 * kc + 8 * (ln >> 4);
    short8 v;
    if (row < NN) {
      const float* ap = &A[(size_t)row * 64 + k0];
#pragma unroll
      for (int j = 0; j < 8; ++j) v[j] = (short)f2b(ap[j]);
    } else {
#pragma unroll
      for (int j = 0; j < 8; ++j) v[j] = 0;
    }
    *(short8*)&lFrag[((kc * 4 + m) * 64 + ln) * 8] = v;
  }
  __syncthreads();
  f32x4 acc[4][2];
#pragma unroll
  for (int m = 0; m < 4; ++m) {
    acc[m][0] = (f32x4){0.f, 0.f, 0.f, 0.f};
    acc[m][1] = (f32x4){0.f, 0.f, 0.f, 0.f};
  }
  short8 bf[2][2];
#pragma unroll
  for (int kc = 0; kc < 2; ++kc)
#pragma unroll
    for (int t = 0; t < 2; ++t) {
      int nt = 2 * w + t;
      bf[kc][t] = *(const short8*)&Wmf[(((nt * 2 + kc) * 64) + lane) * 8];
    }
#pragma unroll
  for (int kc = 0; kc < 2; ++kc)
#pragma unroll
    for (int m = 0; m < 4; ++m) {
      short8 af = *(short8*)&lFrag[((kc * 4 + m) * 64 + lane) * 8];
      acc[m][0] = __builtin_amdgcn_mfma_f32_16x16x32_bf16(af, bf[kc][0], acc[m][0], 0, 0, 0);
      acc[m][1] = __builtin_amdgcn_mfma_f32_16x16x32_bf16(af, bf[kc][1], acc[m][1], 0, 0, 0);
    }
  __syncthreads();
#pragma unroll
  for (int t = 0; t < 2; ++t) {
    int nt = 2 * w + t;
    int ch = 16 * nt + (lane & 15);
    float sc = ls_ab[ch];
    float sh = ls_ab[128 + ch];
    int kc2 = ch >> 5;
    int lgrp = (ch & 31) >> 3;
    int j2 = ch & 7;
#pragma unroll
    for (int m = 0; m < 4; ++m) {
#pragma unroll
      for (int r = 0; r < 4; ++r) {
        float mv = fmaxf(acc[m][t][r] * sc + sh, 0.f);
        int lp = lgrp * 16 + (lane >> 4) * 4 + r;
        lFrag[((kc2 * 4 + m) * 64 + lp) * 8 + j2] = (short)f2b(mv);
      }
    }
  }
  __syncthreads();
  float bias = b2[16 * w + (lane & 15)];
  f32x4 acc2[4];
#pragma unroll
  for (int m = 0; m < 4; ++m) acc2[m] = (f32x4){bias, bias, bias, bias};
#pragma unroll
  for (int kc = 0; kc < 4; ++kc) {
    short8 b2fr = *(const short8*)&W2f[(((w * 4 + kc) * 64) + lane) * 8];
#pragma unroll
    for (int m = 0; m < 4; ++m) {
      short8 af = *(short8*)&lFrag[((kc * 4 + m) * 64 + lane) * 8];
      acc2[m] = __builtin_amdgcn_mfma_f32_16x16x32_bf16(af, b2fr, acc2[m], 0, 0, 0);
    }
  }
  int colch = 16 * w + (lane & 15);
#pragma unroll
  for (int m = 0; m < 4; ++m) {
#pragma unroll
    for (int r = 0; r < 4; ++r) {
      int node = nbase + 16 * m + (lane >> 4) * 4 + r;
      if (node < NN) {
        size_t idx = (size_t)node * 64 + colch;
        float hn = H[idx] + acc2[m][r];
        H[idx] = hn;
        XB[idx] = f2b(fmaxf(hn, 0.f));
      }
    }
  }
}

// ---------------- pool: segmented register max (batch is sorted) ----------------
__global__ __launch_bounds__(256) void k_pool(const float* __restrict__ h,
                                              const int* __restrict__ batch,
                                              unsigned* __restrict__ gmax) {
  int wgid = blockIdx.x * 4 + (threadIdx.x >> 6);
  int lane = threadIdx.x & 63;
  const int per = (NN + POOL_WAVES - 1) / POOL_WAVES;  // 49
  int n0 = wgid * per;
  int n1 = min(n0 + per, NN);
  if (n0 >= NN) return;
  int g = batch[n0];
  float m = -INFINITY;
  for (int node = n0; node < n1; ++node) {
    int b = batch[node];
    if (b != g) {
      atomicMax(&gmax[(g << 6) + lane], fmap(m));
      m = -INFINITY;
      g = b;
    }
    m = fmaxf(m, h[(size_t)node * 64 + lane]);
  }
  atomicMax(&gmax[(g << 6) + lane], fmap(m));
}

__global__ void k_final(const unsigned* __restrict__ gmax, const float* __restrict__ w1,
                        const float* __restrict__ b1, const float* __restrict__ w2,
                        const float* __restrict__ b2, float* __restrict__ out) {
  int b = blockIdx.x;
  __shared__ float g[64], hid[64];
  int t = threadIdx.x;
  if (t < 64) {
    float v = funmap(gmax[b * 64 + t]);
    if (v == -INFINITY) v = 0.f;
    g[t] = v;
  }
  __syncthreads();
  if (t < 64) {
    float acc = b1[t];
    for (int c = 0; c < 64; ++c) acc += g[c] * w1[c * 64 + t];
    hid[t] = fmaxf(acc, 0.f);
  }
  __syncthreads();
  if (t < 80) {
    float acc = b2[t];
    for (int c = 0; c < 64; ++c) acc += hid[c] * w2[c * 80 + t];
    out[b * 80 + t] = acc;
  }
}

extern "C" void kernel_launch(void* const* d_in, const int* in_sizes, int n_in,
                              void* d_out, int out_size, void* d_ws, size_t ws_size,
                              hipStream_t stream) {
  const float* x       = (const float*)d_in[0];
  const int*   ei      = (const int*)d_in[1];
  const int*   batch   = (const int*)d_in[2];
  const float* cin_w1  = (const float*)d_in[3];
  const float* cin_b1  = (const float*)d_in[4];
  const float* cin_g1  = (const float*)d_in[5];
  const float* cin_be1 = (const float*)d_in[6];
  const float* cin_w2  = (const float*)d_in[7];
  const float* cin_b2  = (const float*)d_in[8];
  const float* L_w1    = (const float*)d_in[9];
  const float* L_b1    = (const float*)d_in[10];
  const float* L_g1    = (const float*)d_in[11];
  const float* L_be1   = (const float*)d_in[12];
  const float* L_w2    = (const float*)d_in[13];
  const float* L_b2    = (const float*)d_in[14];
  const float* mlp_w1  = (const float*)d_in[15];
  const float* mlp_b1  = (const float*)d_in[16];
  const float* mlp_w2  = (const float*)d_in[17];
  const float* mlp_b2  = (const float*)d_in[18];

  char* ws = (char*)d_ws;
  size_t off = 0;
  auto alloc = [&](size_t bytes) -> void* {
    void* p = ws + off;
    off = (off + bytes + 255) & ~(size_t)255;
    return p;
  };
  float*          A       = (float*)alloc((size_t)NN * 64 * 4);
  float*          h       = (float*)alloc((size_t)NN * 64 * 4);
  unsigned short* xb      = (unsigned short*)alloc((size_t)NN * 64 * 2);
  int*            rowptr  = (int*)alloc((size_t)(NN + 1) * 4);
  int*            counts  = (int*)alloc((size_t)NN * 4);
  int*            counts8 = (int*)alloc((size_t)HCLS * NN * 4);
  int*            rank    = (int*)alloc((size_t)EE * 4);
  int*            adjsrc  = (int*)alloc((size_t)EE * 4);
  int*            partial = (int*)alloc(NSCAN * 4);
  int*            poffs   = (int*)alloc(128 * 4);
  short*          wmf     = (short*)alloc((size_t)3 * 8192 * 2);
  short*          w2f     = (short*)alloc((size_t)3 * 8192 * 2);
  float*          part    = (float*)alloc((size_t)AG6 * 4160 * 4);
  float*          Sfin    = (float*)alloc((size_t)4 * 4160 * 4);
  float*          ab      = (float*)alloc((size_t)4 * 256 * 4);
  unsigned*       gmax    = (unsigned*)alloc((size_t)BB * 64 * 4);
  (void)ws_size; (void)in_sizes; (void)n_in; (void)out_size;

  const int* srcp = ei;
  const int* dstp = ei + EE;

  // CSR build
  hipMemsetAsync(counts8, 0, (size_t)HCLS * NN * 4, stream);
  k_hist8<<<(EE + 255) / 256, 256, 0, stream>>>(dstp, counts8, rank);
  k_packW<<<192, 256, 0, stream>>>(L_w1, L_w2, wmf, w2f);
  k_off8<<<(NN + 255) / 256, 256, 0, stream>>>(counts8, counts);
  k_scan1<<<NSCAN, 1024, 0, stream>>>(counts, rowptr, partial);
  k_scan2<<<1, 128, 0, stream>>>(partial, poffs, gmax);
  k_scan3<<<NSCAN, 1024, 0, stream>>>(rowptr, poffs);
  k_place<<<(EE + 255) / 256, 256, 0, stream>>>(srcp, dstp, rank, rowptr, counts8, adjsrc);

  const int NB64 = (NN + 63) / 64;  // 1563

  // Layer 0: x[N,6] -> h[N,64] (+ xb = bf16 relu copy)
  {
    float* S = Sfin;
    float* cs = S + 6 * 6;
    float* ab0 = ab;
    k_agg0<<<NN / 4, 256, 0, stream>>>(x, rowptr, adjsrc, A);
    k_ata6<<<AG6, 256, 0, stream>>>(A, part);
    k_redB<<<42, 256, 0, stream>>>(part, S, 42, AG6);
    k_bnprep<6, 12><<<12, 64, 0, stream>>>(S, cs, cin_w1, cin_b1, cin_g1, cin_be1, ab0);
    k_layer<6, 12, 64><<<NB64, 256, 0, stream>>>(A, cin_w1, ab0, cin_w2, cin_b2, h, xb);
  }

  // Layers 1..3: h += MLP(BN(agg(relu(h)) @ W1)) @ W2  (MFMA path)
  for (int i = 0; i < 3; ++i) {
    float* S = Sfin + (size_t)(i + 1) * 4160;
    float* cs = S + 64 * 64;
    float* abi = ab + (size_t)(i + 1) * 256;
    k_aggb<<<NN / 4, 256, 0, stream>>>((const uint4*)xb, h, rowptr, adjsrc, A);
    k_ata64<<<AG64, 256, 0, stream>>>(A, part);
    k_redB<<<4160, 256, 0, stream>>>(part, S, 4160, AG64);
    k_bnprep<64, 128><<<128, 64, 0, stream>>>(S, cs, L_w1 + (size_t)i * 64 * 128,
                                              L_b1 + i * 128, L_g1 + i * 128,
                                              L_be1 + i * 128, abi);
    k_layerM<<<NB64, 256, 0, stream>>>(A, wmf + (size_t)i * 8192, abi,
                                       w2f + (size_t)i * 8192, L_b2 + i * 64, h, xb);
  }

  // Global max pool + final MLP
  k_pool<<<POOL_BLK, 256, 0, stream>>>(h, batch, gmax);
  k_final<<<BB, 128, 0, stream>>>(gmax, mlp_w1, mlp_b1, mlp_w2, mlp_b2, (float*)d_out);
}

// Round 16
// 578.423 us; speedup vs baseline: 1.0529x; 1.0529x over previous
//
#include <hip/hip_runtime.h>

#define NN 100000
#define EE 1600000
#define BB 64
#define NSCAN 98      // ceil(NN/1024)
#define AG6 1024      // grid for F=6 stats
#define AG64 640      // grid for F=64 tiled ata
#define NTILE 1563    // ceil(NN/64)
#define POOL_BLK 512
#define POOL_WAVES (POOL_BLK * 4)
#define HCLS 8        // hist classes (XCD-private count slices)

typedef float f32x4 __attribute__((ext_vector_type(4)));
typedef short short8 __attribute__((ext_vector_type(8)));

__device__ __forceinline__ unsigned fmap(float f) {
  unsigned u = __float_as_uint(f);
  return (u & 0x80000000u) ? ~u : (u | 0x80000000u);
}
__device__ __forceinline__ float funmap(unsigned m) {
  unsigned u = (m & 0x80000000u) ? (m ^ 0x80000000u) : ~m;
  return __uint_as_float(u);
}
__device__ __forceinline__ unsigned short f2b(float f) {
  unsigned u = __float_as_uint(f);
  unsigned r = (u + 0x7FFFu + ((u >> 16) & 1u)) >> 16;
  return (unsigned short)r;
}
__device__ __forceinline__ float b2f(unsigned short s) {
  return __uint_as_float(((unsigned)s) << 16);
}

// ---------------- CSR build (by dst) ----------------
__global__ void k_hist8(const int* __restrict__ dst, int* __restrict__ counts8,
                        int* __restrict__ rank) {
  int i = blockIdx.x * blockDim.x + threadIdx.x;
  int c = blockIdx.x & (HCLS - 1);
  if (i < EE) rank[i] = atomicAdd(&counts8[c * NN + dst[i]], 1);
}

__global__ void k_off8(int* __restrict__ counts8, int* __restrict__ counts) {
  int n = blockIdx.x * blockDim.x + threadIdx.x;
  if (n >= NN) return;
  int t = 0;
#pragma unroll
  for (int c = 0; c < HCLS; ++c) {
    int v = counts8[c * NN + n];
    counts8[c * NN + n] = t;
    t += v;
  }
  counts[n] = t;
}

__global__ void k_scan1(const int* __restrict__ counts, int* __restrict__ rowptr,
                        int* __restrict__ partials) {
  __shared__ int buf[1024];
  int i = blockIdx.x * 1024 + threadIdx.x;
  int v = (i < NN) ? counts[i] : 0;
  buf[threadIdx.x] = v;
  __syncthreads();
  for (int off = 1; off < 1024; off <<= 1) {
    int t = (threadIdx.x >= off) ? buf[threadIdx.x - off] : 0;
    __syncthreads();
    buf[threadIdx.x] += t;
    __syncthreads();
  }
  int incl = buf[threadIdx.x];
  if (i < NN) rowptr[i] = incl - v;
  if (threadIdx.x == 1023) partials[blockIdx.x] = incl;
}

__global__ void k_scan2(const int* __restrict__ partials, int* __restrict__ poffs,
                        unsigned* __restrict__ gmax) {
  __shared__ int buf[128];
  int t = threadIdx.x;
  int v = (t < NSCAN) ? partials[t] : 0;
  buf[t] = v;
  __syncthreads();
  for (int off = 1; off < 128; off <<= 1) {
    int u = (t >= off) ? buf[t - off] : 0;
    __syncthreads();
    buf[t] += u;
    __syncthreads();
  }
  poffs[t] = buf[t] - v;
  for (int i = t; i < BB * 64; i += 128) gmax[i] = 0x007FFFFFu;  // fmap(-inf)
}

__global__ void k_scan3(int* __restrict__ rowptr, const int* __restrict__ poffs) {
  int i = blockIdx.x * 1024 + threadIdx.x;
  if (i < NN) rowptr[i] += poffs[blockIdx.x];
  if (i == 0) rowptr[NN] = EE;
}

__global__ __launch_bounds__(256) void k_place(const int* __restrict__ src,
                                               const int* __restrict__ dst,
                                               const int* __restrict__ rank,
                                               const int* __restrict__ rowptr,
                                               const int* __restrict__ counts8,
                                               int* __restrict__ adjsrc) {
  int i = blockIdx.x * blockDim.x + threadIdx.x;
  if (i < EE) {
    int c = (i >> 8) & (HCLS - 1);
    int d = dst[i];
    adjsrc[rowptr[d] + counts8[c * NN + d] + rank[i]] = src[i];
  }
}

// ---------------- layer-0 aggregation: f32 gather, F=6 ----------------
__global__ __launch_bounds__(256) void k_agg0(const float* __restrict__ xin,
                                              const int* __restrict__ rowptr,
                                              const int* __restrict__ adjsrc,
                                              float* __restrict__ out) {
  int w = __builtin_amdgcn_readfirstlane(threadIdx.x >> 6);
  int lane = threadIdx.x & 63;
  int wid = blockIdx.x * 4 + w;
  if (wid >= NN) return;
  int s = rowptr[wid], e = rowptr[wid + 1];
  bool act = lane < 6;
  float den = 0.f, num = 0.f;
  int i = s;
  for (; i + 3 < e; i += 4) {
    int n0 = adjsrc[i], n1 = adjsrc[i + 1], n2 = adjsrc[i + 2], n3 = adjsrc[i + 3];
    float v0 = act ? xin[(size_t)n0 * 6 + lane] : 0.f;
    float v1 = act ? xin[(size_t)n1 * 6 + lane] : 0.f;
    float v2 = act ? xin[(size_t)n2 * 6 + lane] : 0.f;
    float v3 = act ? xin[(size_t)n3 * 6 + lane] : 0.f;
    float m0 = fminf(fmaxf(v0, 0.f) + 1e-7f, 80.f);
    float m1 = fminf(fmaxf(v1, 0.f) + 1e-7f, 80.f);
    float m2 = fminf(fmaxf(v2, 0.f) + 1e-7f, 80.f);
    float m3 = fminf(fmaxf(v3, 0.f) + 1e-7f, 80.f);
    float e0 = __expf(m0), e1 = __expf(m1), e2 = __expf(m2), e3 = __expf(m3);
    den += (e0 + e1) + (e2 + e3);
    num += (m0 * e0 + m1 * e1) + (m2 * e2 + m3 * e3);
  }
  for (; i < e; ++i) {
    int n0 = adjsrc[i];
    float v0 = act ? xin[(size_t)n0 * 6 + lane] : 0.f;
    float m0 = fminf(fmaxf(v0, 0.f) + 1e-7f, 80.f);
    float e0 = __expf(m0);
    den += e0;
    num += m0 * e0;
  }
  if (act) {
    float xr = xin[(size_t)wid * 6 + lane];
    out[(size_t)wid * 6 + lane] = num / (den + 1e-16f) + xr;
  }
}

// ---------------- layers 1-3 aggregation: bf16 gather, f32 residual, bf16 out ----
__global__ __launch_bounds__(256) void k_aggb(const unsigned short* __restrict__ xb,
                                              const float* __restrict__ h,
                                              const int* __restrict__ rowptr,
                                              const int* __restrict__ adjsrc,
                                              unsigned short* __restrict__ outb) {
  int w = __builtin_amdgcn_readfirstlane(threadIdx.x >> 6);
  int lane = threadIdx.x & 63;
  int wid = blockIdx.x * 4 + w;
  if (wid >= NN) return;
  int s = rowptr[wid], e = rowptr[wid + 1];
  float den = 0.f, num = 0.f;
  int i = s;
  for (; i + 3 < e; i += 4) {
    int n0 = adjsrc[i], n1 = adjsrc[i + 1], n2 = adjsrc[i + 2], n3 = adjsrc[i + 3];
    float v0 = b2f(xb[(size_t)n0 * 64 + lane]);
    float v1 = b2f(xb[(size_t)n1 * 64 + lane]);
    float v2 = b2f(xb[(size_t)n2 * 64 + lane]);
    float v3 = b2f(xb[(size_t)n3 * 64 + lane]);
    float m0 = fminf(v0 + 1e-7f, 80.f);   // xb already relu'd
    float m1 = fminf(v1 + 1e-7f, 80.f);
    float m2 = fminf(v2 + 1e-7f, 80.f);
    float m3 = fminf(v3 + 1e-7f, 80.f);
    float e0 = __expf(m0), e1 = __expf(m1), e2 = __expf(m2), e3 = __expf(m3);
    den += (e0 + e1) + (e2 + e3);
    num += (m0 * e0 + m1 * e1) + (m2 * e2 + m3 * e3);
  }
  for (; i < e; ++i) {
    int n0 = adjsrc[i];
    float v0 = b2f(xb[(size_t)n0 * 64 + lane]);
    float m0 = fminf(v0 + 1e-7f, 80.f);
    float e0 = __expf(m0);
    den += e0;
    num += m0 * e0;
  }
  float res = fmaxf(h[(size_t)wid * 64 + lane], 0.f);
  outb[(size_t)wid * 64 + lane] = f2b(num / (den + 1e-16f) + res);
}

// ---------------- F=6 stats: shfl outer product (cheap) ----------------
__global__ __launch_bounds__(256) void k_ata6(const float* __restrict__ A,
                                              float* __restrict__ part) {
  constexpr int F = 6;
  int lane = threadIdx.x & 63;
  int w = __builtin_amdgcn_readfirstlane(threadIdx.x >> 6);
  bool act = lane < F;
  float Sloc[F];
#pragma unroll
  for (int c = 0; c < F; ++c) Sloc[c] = 0.f;
  float csloc = 0.f;
  int NW = gridDim.x * 4;
  for (int node = blockIdx.x * 4 + w; node < NN; node += NW) {
    float a = act ? A[(size_t)node * F + lane] : 0.f;
    csloc += a;
#pragma unroll
    for (int c = 0; c < F; ++c) {
      float ac = __shfl(a, c, 64);
      Sloc[c] += ac * a;
    }
  }
  __shared__ float ls[F * F + F];
  for (int idx = threadIdx.x; idx < F * F + F; idx += 256) ls[idx] = 0.f;
  __syncthreads();
  if (act) {
#pragma unroll
    for (int c = 0; c < F; ++c) atomicAdd(&ls[c * F + lane], Sloc[c]);
    atomicAdd(&ls[F * F + lane], csloc);
  }
  __syncthreads();
  float* dstp = part + (size_t)blockIdx.x * (F * F + F);
  for (int idx = threadIdx.x; idx < F * F + F; idx += 256) dstp[idx] = ls[idx];
}

// ---------------- F=64 stats: LDS-tiled rank-1 accumulation (bf16 input) -------
__global__ __launch_bounds__(256) void k_ata64(const unsigned short* __restrict__ Ab,
                                               float* __restrict__ part) {
  __shared__ float lA[64 * 64];   // [node][ch] (f32, converted at staging)
  __shared__ float lcs[64];
  int tid = threadIdx.x;
  int tx = tid & 15, ty = tid >> 4;
  float acc[4][4];
#pragma unroll
  for (int i = 0; i < 4; ++i)
#pragma unroll
    for (int j = 0; j < 4; ++j) acc[i][j] = 0.f;
  float cs0 = 0.f, cs1 = 0.f, cs2 = 0.f, cs3 = 0.f;
  if (tid < 64) lcs[tid] = 0.f;
  const uint2* A2 = (const uint2*)Ab;
  for (int tile = blockIdx.x; tile < NTILE; tile += gridDim.x) {
    int nbase = tile * 64;
    __syncthreads();   // protect lA from previous iteration's readers
#pragma unroll
    for (int k = 0; k < 4; ++k) {
      int node = ty + k * 16;
      int gn = nbase + node;
      float4 v;
      if (gn < NN) {
        uint2 u = A2[(size_t)gn * 16 + tx];
        v.x = b2f((unsigned short)(u.x & 0xffff));
        v.y = b2f((unsigned short)(u.x >> 16));
        v.z = b2f((unsigned short)(u.y & 0xffff));
        v.w = b2f((unsigned short)(u.y >> 16));
      } else {
        v = make_float4(0.f, 0.f, 0.f, 0.f);
      }
      *(float4*)&lA[node * 64 + tx * 4] = v;
      cs0 += v.x; cs1 += v.y; cs2 += v.z; cs3 += v.w;
    }
    __syncthreads();
#pragma unroll 4
    for (int node = 0; node < 64; ++node) {
      float4 rv = *(const float4*)&lA[node * 64 + ty * 4];
      float4 cv = *(const float4*)&lA[node * 64 + tx * 4];
      acc[0][0] += rv.x * cv.x; acc[0][1] += rv.x * cv.y;
      acc[0][2] += rv.x * cv.z; acc[0][3] += rv.x * cv.w;
      acc[1][0] += rv.y * cv.x; acc[1][1] += rv.y * cv.y;
      acc[1][2] += rv.y * cv.z; acc[1][3] += rv.y * cv.w;
      acc[2][0] += rv.z * cv.x; acc[2][1] += rv.z * cv.y;
      acc[2][2] += rv.z * cv.z; acc[2][3] += rv.z * cv.w;
      acc[3][0] += rv.w * cv.x; acc[3][1] += rv.w * cv.y;
      acc[3][2] += rv.w * cv.z; acc[3][3] += rv.w * cv.w;
    }
  }
  __syncthreads();
  atomicAdd(&lcs[tx * 4 + 0], cs0);
  atomicAdd(&lcs[tx * 4 + 1], cs1);
  atomicAdd(&lcs[tx * 4 + 2], cs2);
  atomicAdd(&lcs[tx * 4 + 3], cs3);
  float* dstp = part + (size_t)blockIdx.x * 4160;
#pragma unroll
  for (int i = 0; i < 4; ++i)
#pragma unroll
    for (int j = 0; j < 4; ++j)
      dstp[(ty * 4 + i) * 64 + tx * 4 + j] = acc[i][j];
  __syncthreads();
  if (tid < 64) dstp[4096 + tid] = lcs[tid];
}

// ---------------- reduce partials: block-per-index tree ----------------
__global__ void k_redB(const float* __restrict__ part, float* __restrict__ out,
                       int stride, int ngrid) {
  __shared__ float buf[256];
  int i = blockIdx.x;
  float s = 0.f;
  for (int g = threadIdx.x; g < ngrid; g += 256) s += part[(size_t)g * stride + i];
  buf[threadIdx.x] = s;
  __syncthreads();
  for (int off = 128; off; off >>= 1) {
    if (threadIdx.x < off) buf[threadIdx.x] += buf[threadIdx.x + off];
    __syncthreads();
  }
  if (threadIdx.x == 0) out[i] = buf[0];
}

// ---------------- BN params from covariance ----------------
template<int FIN, int FMID>
__global__ void k_bnprep(const float* __restrict__ S, const float* __restrict__ cs,
                         const float* __restrict__ Wm, const float* __restrict__ bm,
                         const float* __restrict__ gamma, const float* __restrict__ beta,
                         float* __restrict__ ab) {
  int j = blockIdx.x;
  int lane = threadIdx.x;
  bool act = (FIN == 64) || (lane < FIN);
  float wj = act ? Wm[lane * FMID + j] : 0.f;
  float mb = act ? cs[lane] * (1.f / NN) : 0.f;
  float t = mb * wj;
#pragma unroll
  for (int off = 32; off; off >>= 1) t += __shfl_xor(t, off, 64);
  float mulin = t;
  float acc = 0.f;
  for (int c = 0; c < FIN; ++c) {
    float sv = act ? S[c * FIN + lane] : 0.f;
    float p = sv * wj;
#pragma unroll
    for (int off = 32; off; off >>= 1) p += __shfl_xor(p, off, 64);
    acc += p * __shfl(wj, c, 64);
  }
  if (lane == 0) {
    float var = acc * (1.f / NN) - mulin * mulin;
    float rstd = rsqrtf(fmaxf(var, 0.f) + 1e-5f);
    float sc = rstd * gamma[j];
    ab[j] = sc;
    ab[FMID + j] = beta[j] - mulin * sc;
  }
}

// ---------------- layer-0 fused GEMM (VALU path, FIN=6) ----------------
template<int FIN, int FMID, int FOUT>
__global__ __launch_bounds__(256) void k_layer(const float* __restrict__ A,
                                               const float* __restrict__ Wm,
                                               const float* __restrict__ ab,
                                               const float* __restrict__ W2,
                                               const float* __restrict__ b2,
                                               float* __restrict__ H,
                                               unsigned short* __restrict__ XB) {
  constexpr int SM = FMID + 1;
  constexpr int MW = FMID / 4;
  constexpr int OW = FOUT / 4;
  __shared__ float lA[FIN * 65];
  __shared__ float lH_sep[64 * SM];
  int tid = threadIdx.x;
  int lane = tid & 63;
  int w = __builtin_amdgcn_readfirstlane(tid >> 6);
  int nbase = blockIdx.x * 64;
  for (int e = tid; e < 64 * FIN; e += 256) {
    int node = e / FIN, c = e - node * FIN;
    int gn = nbase + node;
    lA[c * 65 + node] = (gn < NN) ? A[(size_t)gn * FIN + c] : 0.f;
  }
  __syncthreads();
  float acc[MW];
#pragma unroll
  for (int j = 0; j < MW; ++j) acc[j] = 0.f;
#pragma unroll 4
  for (int c = 0; c < FIN; ++c) {
    float a = lA[c * 65 + lane];
#pragma unroll
    for (int j = 0; j < MW; ++j) acc[j] += a * Wm[c * FMID + w * MW + j];
  }
#pragma unroll
  for (int j = 0; j < MW; ++j) {
    float sc = ab[w * MW + j];
    float sh = ab[FMID + w * MW + j];
    lH_sep[lane * SM + w * MW + j] = fmaxf(acc[j] * sc + sh, 0.f);
  }
  __syncthreads();
  float acc2[OW];
#pragma unroll
  for (int j = 0; j < OW; ++j) acc2[j] = b2[w * OW + j];
#pragma unroll 4
  for (int c = 0; c < FMID; ++c) {
    float hv = lH_sep[lane * SM + c];
#pragma unroll
    for (int j = 0; j < OW; ++j) acc2[j] += hv * W2[c * FOUT + w * OW + j];
  }
  int node = nbase + lane;
  if (node < NN) {
    size_t base = (size_t)node * FOUT + w * OW;
#pragma unroll
    for (int j = 0; j < OW; ++j) {
      float hn = fmaxf(acc2[j], 0.f);
      H[base + j] = hn;
      XB[base + j] = f2b(hn);
    }
  }
}

// ---------------- weight pre-pack to MFMA fragment order (bf16) ----------------
__global__ void k_packW(const float* __restrict__ L_w1, const float* __restrict__ L_w2,
                        short* __restrict__ wmf, short* __restrict__ w2f) {
  int idx = blockIdx.x * 256 + threadIdx.x;
  if (idx >= 3 * 16384) return;
  int layer = idx / 16384;
  int r = idx - layer * 16384;
  bool isW2 = r >= 8192;
  int e = isW2 ? r - 8192 : r;
  int j = e & 7, lane = (e >> 3) & 63, t = e >> 9;
  int kgrp = lane >> 4, nlow = lane & 15;
  if (!isW2) {
    int nt = t >> 1, kc = t & 1;
    int k = kc * 32 + 8 * kgrp + j, n = nt * 16 + nlow;
    wmf[(size_t)layer * 8192 + e] = (short)f2b(L_w1[(size_t)layer * 64 * 128 + k * 128 + n]);
  } else {
    int nt = t >> 2, kc = t & 3;
    int k = kc * 32 + 8 * kgrp + j, n = nt * 16 + nlow;
    w2f[(size_t)layer * 8192 + e] = (short)f2b(L_w2[(size_t)layer * 128 * 64 + k * 64 + n]);
  }
}

// ---------------- MFMA fused layer (layers 1-3), bf16 A input ----------------
__global__ __launch_bounds__(256) void k_layerM(const unsigned short* __restrict__ Ab,
                                                const short* __restrict__ Wmf,
                                                const float* __restrict__ ab,
                                                const short* __restrict__ W2f,
                                                const float* __restrict__ b2,
                                                float* __restrict__ H,
                                                unsigned short* __restrict__ XB) {
  __shared__ short lFrag[8192];   // 16KB; GEMM1 a-frags then GEMM2 a-frags
  __shared__ float ls_ab[256];
  int tid = threadIdx.x;
  int lane = tid & 63;
  int w = tid >> 6;
  int nbase = blockIdx.x * 64;
  ls_ab[tid] = ab[tid];
#pragma unroll
  for (int it = 0; it < 2; ++it) {
    int e = tid + 256 * it;
    int ln = e & 63;
    int m = (e >> 6) & 3;
    int kc = e >> 8;
    int row = nbase + 16 * m + (ln & 15);
    int k0 = 32 * kc + 8 * (ln >> 4);
    short8 v;
    if (row < NN) {
      v = *(const short8*)&Ab[(size_t)row * 64 + k0];   // direct bf16 copy
    } else {
#pragma unroll
      for (int j = 0; j < 8; ++j) v[j] = 0;
    }
    *(short8*)&lFrag[((kc * 4 + m) * 64 + ln) * 8] = v;
  }
  __syncthreads();
  f32x4 acc[4][2];
#pragma unroll
  for (int m = 0; m < 4; ++m) {
    acc[m][0] = (f32x4){0.f, 0.f, 0.f, 0.f};
    acc[m][1] = (f32x4){0.f, 0.f, 0.f, 0.f};
  }
  short8 bf[2][2];
#pragma unroll
  for (int kc = 0; kc < 2; ++kc)
#pragma unroll
    for (int t = 0; t < 2; ++t) {
      int nt = 2 * w + t;
      bf[kc][t] = *(const short8*)&Wmf[(((nt * 2 + kc) * 64) + lane) * 8];
    }
#pragma unroll
  for (int kc = 0; kc < 2; ++kc)
#pragma unroll
    for (int m = 0; m < 4; ++m) {
      short8 af = *(short8*)&lFrag[((kc * 4 + m) * 64 + lane) * 8];
      acc[m][0] = __builtin_amdgcn_mfma_f32_16x16x32_bf16(af, bf[kc][0], acc[m][0], 0, 0, 0);
      acc[m][1] = __builtin_amdgcn_mfma_f32_16x16x32_bf16(af, bf[kc][1], acc[m][1], 0, 0, 0);
    }
  __syncthreads();
#pragma unroll
  for (int t = 0; t < 2; ++t) {
    int nt = 2 * w + t;
    int ch = 16 * nt + (lane & 15);
    float sc = ls_ab[ch];
    float sh = ls_ab[128 + ch];
    int kc2 = ch >> 5;
    int lgrp = (ch & 31) >> 3;
    int j2 = ch & 7;
#pragma unroll
    for (int m = 0; m < 4; ++m) {
#pragma unroll
      for (int r = 0; r < 4; ++r) {
        float mv = fmaxf(acc[m][t][r] * sc + sh, 0.f);
        int lp = lgrp * 16 + (lane >> 4) * 4 + r;
        lFrag[((kc2 * 4 + m) * 64 + lp) * 8 + j2] = (short)f2b(mv);
      }
    }
  }
  __syncthreads();
  float bias = b2[16 * w + (lane & 15)];
  f32x4 acc2[4];
#pragma unroll
  for (int m = 0; m < 4; ++m) acc2[m] = (f32x4){bias, bias, bias, bias};
#pragma unroll
  for (int kc = 0; kc < 4; ++kc) {
    short8 b2fr = *(const short8*)&W2f[(((w * 4 + kc) * 64) + lane) * 8];
#pragma unroll
    for (int m = 0; m < 4; ++m) {
      short8 af = *(short8*)&lFrag[((kc * 4 + m) * 64 + lane) * 8];
      acc2[m] = __builtin_amdgcn_mfma_f32_16x16x32_bf16(af, b2fr, acc2[m], 0, 0, 0);
    }
  }
  int colch = 16 * w + (lane & 15);
#pragma unroll
  for (int m = 0; m < 4; ++m) {
#pragma unroll
    for (int r = 0; r < 4; ++r) {
      int node = nbase + 16 * m + (lane >> 4) * 4 + r;
      if (node < NN) {
        size_t idx = (size_t)node * 64 + colch;
        float hn = H[idx] + acc2[m][r];
        H[idx] = hn;
        XB[idx] = f2b(fmaxf(hn, 0.f));
      }
    }
  }
}

// ---------------- pool: segmented register max (batch is sorted) ----------------
__global__ __launch_bounds__(256) void k_pool(const float* __restrict__ h,
                                              const int* __restrict__ batch,
                                              unsigned* __restrict__ gmax) {
  int wgid = blockIdx.x * 4 + (threadIdx.x >> 6);
  int lane = threadIdx.x & 63;
  const int per = (NN + POOL_WAVES - 1) / POOL_WAVES;  // 49
  int n0 = wgid * per;
  int n1 = min(n0 + per, NN);
  if (n0 >= NN) return;
  int g = batch[n0];
  float m = -INFINITY;
  for (int node = n0; node < n1; ++node) {
    int b = batch[node];
    if (b != g) {
      atomicMax(&gmax[(g << 6) + lane], fmap(m));
      m = -INFINITY;
      g = b;
    }
    m = fmaxf(m, h[(size_t)node * 64 + lane]);
  }
  atomicMax(&gmax[(g << 6) + lane], fmap(m));
}

__global__ void k_final(const unsigned* __restrict__ gmax, const float* __restrict__ w1,
                        const float* __restrict__ b1, const float* __restrict__ w2,
                        const float* __restrict__ b2, float* __restrict__ out) {
  int b = blockIdx.x;
  __shared__ float g[64], hid[64];
  int t = threadIdx.x;
  if (t < 64) {
    float v = funmap(gmax[b * 64 + t]);
    if (v == -INFINITY) v = 0.f;
    g[t] = v;
  }
  __syncthreads();
  if (t < 64) {
    float acc = b1[t];
    for (int c = 0; c < 64; ++c) acc += g[c] * w1[c * 64 + t];
    hid[t] = fmaxf(acc, 0.f);
  }
  __syncthreads();
  if (t < 80) {
    float acc = b2[t];
    for (int c = 0; c < 64; ++c) acc += hid[c] * w2[c * 80 + t];
    out[b * 80 + t] = acc;
  }
}

extern "C" void kernel_launch(void* const* d_in, const int* in_sizes, int n_in,
                              void* d_out, int out_size, void* d_ws, size_t ws_size,
                              hipStream_t stream) {
  const float* x       = (const float*)d_in[0];
  const int*   ei      = (const int*)d_in[1];
  const int*   batch   = (const int*)d_in[2];
  const float* cin_w1  = (const float*)d_in[3];
  const float* cin_b1  = (const float*)d_in[4];
  const float* cin_g1  = (const float*)d_in[5];
  const float* cin_be1 = (const float*)d_in[6];
  const float* cin_w2  = (const float*)d_in[7];
  const float* cin_b2  = (const float*)d_in[8];
  const float* L_w1    = (const float*)d_in[9];
  const float* L_b1    = (const float*)d_in[10];
  const float* L_g1    = (const float*)d_in[11];
  const float* L_be1   = (const float*)d_in[12];
  const float* L_w2    = (const float*)d_in[13];
  const float* L_b2    = (const float*)d_in[14];
  const float* mlp_w1  = (const float*)d_in[15];
  const float* mlp_b1  = (const float*)d_in[16];
  const float* mlp_w2  = (const float*)d_in[17];
  const float* mlp_b2  = (const float*)d_in[18];

  char* ws = (char*)d_ws;
  size_t off = 0;
  auto alloc = [&](size_t bytes) -> void* {
    void* p = ws + off;
    off = (off + bytes + 255) & ~(size_t)255;
    return p;
  };
  float*          A       = (float*)alloc((size_t)NN * 64 * 4);   // layer-0 f32 agg
  unsigned short* ab16    = (unsigned short*)alloc((size_t)NN * 64 * 2);  // layers 1-3 agg (bf16)
  float*          h       = (float*)alloc((size_t)NN * 64 * 4);
  unsigned short* xb      = (unsigned short*)alloc((size_t)NN * 64 * 2);
  int*            rowptr  = (int*)alloc((size_t)(NN + 1) * 4);
  int*            counts  = (int*)alloc((size_t)NN * 4);
  int*            counts8 = (int*)alloc((size_t)HCLS * NN * 4);
  int*            rank    = (int*)alloc((size_t)EE * 4);
  int*            adjsrc  = (int*)alloc((size_t)EE * 4);
  int*            partial = (int*)alloc(NSCAN * 4);
  int*            poffs   = (int*)alloc(128 * 4);
  short*          wmf     = (short*)alloc((size_t)3 * 8192 * 2);
  short*          w2f     = (short*)alloc((size_t)3 * 8192 * 2);
  float*          part    = (float*)alloc((size_t)AG6 * 4160 * 4);
  float*          Sfin    = (float*)alloc((size_t)4 * 4160 * 4);
  float*          ab      = (float*)alloc((size_t)4 * 256 * 4);
  unsigned*       gmax    = (unsigned*)alloc((size_t)BB * 64 * 4);
  (void)ws_size; (void)in_sizes; (void)n_in; (void)out_size;

  const int* srcp = ei;
  const int* dstp = ei + EE;

  // CSR build
  hipMemsetAsync(counts8, 0, (size_t)HCLS * NN * 4, stream);
  k_hist8<<<(EE + 255) / 256, 256, 0, stream>>>(dstp, counts8, rank);
  k_packW<<<192, 256, 0, stream>>>(L_w1, L_w2, wmf, w2f);
  k_off8<<<(NN + 255) / 256, 256, 0, stream>>>(counts8, counts);
  k_scan1<<<NSCAN, 1024, 0, stream>>>(counts, rowptr, partial);
  k_scan2<<<1, 128, 0, stream>>>(partial, poffs, gmax);
  k_scan3<<<NSCAN, 1024, 0, stream>>>(rowptr, poffs);
  k_place<<<(EE + 255) / 256, 256, 0, stream>>>(srcp, dstp, rank, rowptr, counts8, adjsrc);

  const int NB64 = (NN + 63) / 64;  // 1563

  // Layer 0: x[N,6] -> h[N,64] (+ xb = bf16 relu copy)
  {
    float* S = Sfin;
    float* cs = S + 6 * 6;
    float* ab0 = ab;
    k_agg0<<<NN / 4, 256, 0, stream>>>(x, rowptr, adjsrc, A);
    k_ata6<<<AG6, 256, 0, stream>>>(A, part);
    k_redB<<<42, 256, 0, stream>>>(part, S, 42, AG6);
    k_bnprep<6, 12><<<12, 64, 0, stream>>>(S, cs, cin_w1, cin_b1, cin_g1, cin_be1, ab0);
    k_layer<6, 12, 64><<<NB64, 256, 0, stream>>>(A, cin_w1, ab0, cin_w2, cin_b2, h, xb);
  }

  // Layers 1..3: h += MLP(BN(agg(relu(h)) @ W1)) @ W2  (MFMA path, bf16 A)
  for (int i = 0; i < 3; ++i) {
    float* S = Sfin + (size_t)(i + 1) * 4160;
    float* cs = S + 64 * 64;
    float* abi = ab + (size_t)(i + 1) * 256;
    k_aggb<<<NN / 4, 256, 0, stream>>>(xb, h, rowptr, adjsrc, ab16);
    k_ata64<<<AG64, 256, 0, stream>>>(ab16, part);
    k_redB<<<4160, 256, 0, stream>>>(part, S, 4160, AG64);
    k_bnprep<64, 128><<<128, 64, 0, stream>>>(S, cs, L_w1 + (size_t)i * 64 * 128,
                                              L_b1 + i * 128, L_g1 + i * 128,
                                              L_be1 + i * 128, abi);
    k_layerM<<<NB64, 256, 0, stream>>>(ab16, wmf + (size_t)i * 8192, abi,
                                       w2f + (size_t)i * 8192, L_b2 + i * 64, h, xb);
  }

  // Global max pool + final MLP
  k_pool<<<POOL_BLK, 256, 0, stream>>>(h, batch, gmax);
  k_final<<<BB, 128, 0, stream>>>(gmax, mlp_w1, mlp_b1, mlp_w2, mlp_b2, (float*)d_out);
}

// Round 17
// 548.396 us; speedup vs baseline: 1.1106x; 1.0548x over previous
//
#include <hip/hip_runtime.h>

#define NN 100000
#define EE 1600000
#define BB 64
#define NSCAN 98      // ceil(NN/1024)
#define AG6 1024      // grid for F=6 stats
#define AG64 640      // grid for F=64 tiled ata
#define NTILE 1563    // ceil(NN/64)
#define POOL_BLK 512
#define POOL_WAVES (POOL_BLK * 4)
#define HCLS 8        // hist classes (XCD-private count slices)

typedef float f32x4 __attribute__((ext_vector_type(4)));
typedef short short8 __attribute__((ext_vector_type(8)));

__device__ __forceinline__ unsigned fmap(float f) {
  unsigned u = __float_as_uint(f);
  return (u & 0x80000000u) ? ~u : (u | 0x80000000u);
}
__device__ __forceinline__ float funmap(unsigned m) {
  unsigned u = (m & 0x80000000u) ? (m ^ 0x80000000u) : ~m;
  return __uint_as_float(u);
}
__device__ __forceinline__ unsigned short f2b(float f) {
  unsigned u = __float_as_uint(f);
  unsigned r = (u + 0x7FFFu + ((u >> 16) & 1u)) >> 16;
  return (unsigned short)r;
}
__device__ __forceinline__ float b2f(unsigned short s) {
  return __uint_as_float(((unsigned)s) << 16);
}

// ---------------- CSR build (by dst) ----------------
__global__ void k_hist8(const int* __restrict__ dst, int* __restrict__ counts8,
                        int* __restrict__ rank) {
  int i = blockIdx.x * blockDim.x + threadIdx.x;
  int c = blockIdx.x & (HCLS - 1);
  if (i < EE) rank[i] = atomicAdd(&counts8[c * NN + dst[i]], 1);
}

__global__ void k_off8(int* __restrict__ counts8, int* __restrict__ counts) {
  int n = blockIdx.x * blockDim.x + threadIdx.x;
  if (n >= NN) return;
  int t = 0;
#pragma unroll
  for (int c = 0; c < HCLS; ++c) {
    int v = counts8[c * NN + n];
    counts8[c * NN + n] = t;
    t += v;
  }
  counts[n] = t;
}

__global__ void k_scan1(const int* __restrict__ counts, int* __restrict__ rowptr,
                        int* __restrict__ partials) {
  __shared__ int buf[1024];
  int i = blockIdx.x * 1024 + threadIdx.x;
  int v = (i < NN) ? counts[i] : 0;
  buf[threadIdx.x] = v;
  __syncthreads();
  for (int off = 1; off < 1024; off <<= 1) {
    int t = (threadIdx.x >= off) ? buf[threadIdx.x - off] : 0;
    __syncthreads();
    buf[threadIdx.x] += t;
    __syncthreads();
  }
  int incl = buf[threadIdx.x];
  if (i < NN) rowptr[i] = incl - v;
  if (threadIdx.x == 1023) partials[blockIdx.x] = incl;
}

__global__ void k_scan2(const int* __restrict__ partials, int* __restrict__ poffs,
                        unsigned* __restrict__ gmax) {
  __shared__ int buf[128];
  int t = threadIdx.x;
  int v = (t < NSCAN) ? partials[t] : 0;
  buf[t] = v;
  __syncthreads();
  for (int off = 1; off < 128; off <<= 1) {
    int u = (t >= off) ? buf[t - off] : 0;
    __syncthreads();
    buf[t] += u;
    __syncthreads();
  }
  poffs[t] = buf[t] - v;
  for (int i = t; i < BB * 64; i += 128) gmax[i] = 0x007FFFFFu;  // fmap(-inf)
}

__global__ void k_scan3(int* __restrict__ rowptr, const int* __restrict__ poffs) {
  int i = blockIdx.x * 1024 + threadIdx.x;
  if (i < NN) rowptr[i] += poffs[blockIdx.x];
  if (i == 0) rowptr[NN] = EE;
}

__global__ __launch_bounds__(256) void k_place(const int* __restrict__ src,
                                               const int* __restrict__ dst,
                                               const int* __restrict__ rank,
                                               const int* __restrict__ rowptr,
                                               const int* __restrict__ counts8,
                                               int* __restrict__ adjsrc) {
  int i = blockIdx.x * blockDim.x + threadIdx.x;
  if (i < EE) {
    int c = (i >> 8) & (HCLS - 1);
    int d = dst[i];
    adjsrc[rowptr[d] + counts8[c * NN + d] + rank[i]] = src[i];
  }
}

// ---------------- layer-0 aggregation: 8-edge-parallel, F=6 ----------------
// lane = (eslot<<3)|ch: 8 edge-slots x 8 channel-slots (ch<6 active).
// Serial trip count drops ~16 -> 2; merge across eslots via 3 shfl_xor.
__global__ __launch_bounds__(256) void k_agg0(const float* __restrict__ xin,
                                              const int* __restrict__ rowptr,
                                              const int* __restrict__ adjsrc,
                                              float* __restrict__ out) {
  int w = __builtin_amdgcn_readfirstlane(threadIdx.x >> 6);
  int lane = threadIdx.x & 63;
  int wid = blockIdx.x * 4 + w;
  if (wid >= NN) return;
  int eslot = lane >> 3;   // 0..7
  int ch = lane & 7;       // 0..7, <6 active
  bool act = ch < 6;
  int s = rowptr[wid], e = rowptr[wid + 1];
  float den = 0.f, num = 0.f;
  for (int base = s; base < e; base += 8) {
    int ei = base + eslot;
    bool valid = ei < e;
    int n0 = adjsrc[valid ? ei : s];
    float v = act ? xin[(size_t)n0 * 6 + ch] : 0.f;
    float m = fminf(fmaxf(v, 0.f) + 1e-7f, 80.f);
    float ex = valid ? __expf(m) : 0.f;
    den += ex;
    num += m * ex;
  }
#pragma unroll
  for (int off = 8; off < 64; off <<= 1) {
    den += __shfl_xor(den, off, 64);
    num += __shfl_xor(num, off, 64);
  }
  if (eslot == 0 && act) {
    float xr = xin[(size_t)wid * 6 + ch];
    out[(size_t)wid * 6 + ch] = num / (den + 1e-16f) + xr;
  }
}

// ---------------- layers 1-3 aggregation: bf16 gather, f32 residual, bf16 out ----
__global__ __launch_bounds__(256) void k_aggb(const unsigned short* __restrict__ xb,
                                              const float* __restrict__ h,
                                              const int* __restrict__ rowptr,
                                              const int* __restrict__ adjsrc,
                                              unsigned short* __restrict__ outb) {
  int w = __builtin_amdgcn_readfirstlane(threadIdx.x >> 6);
  int lane = threadIdx.x & 63;
  int wid = blockIdx.x * 4 + w;
  if (wid >= NN) return;
  int s = rowptr[wid], e = rowptr[wid + 1];
  float den = 0.f, num = 0.f;
  int i = s;
  for (; i + 3 < e; i += 4) {
    int n0 = adjsrc[i], n1 = adjsrc[i + 1], n2 = adjsrc[i + 2], n3 = adjsrc[i + 3];
    float v0 = b2f(xb[(size_t)n0 * 64 + lane]);
    float v1 = b2f(xb[(size_t)n1 * 64 + lane]);
    float v2 = b2f(xb[(size_t)n2 * 64 + lane]);
    float v3 = b2f(xb[(size_t)n3 * 64 + lane]);
    float m0 = fminf(v0 + 1e-7f, 80.f);   // xb already relu'd
    float m1 = fminf(v1 + 1e-7f, 80.f);
    float m2 = fminf(v2 + 1e-7f, 80.f);
    float m3 = fminf(v3 + 1e-7f, 80.f);
    float e0 = __expf(m0), e1 = __expf(m1), e2 = __expf(m2), e3 = __expf(m3);
    den += (e0 + e1) + (e2 + e3);
    num += (m0 * e0 + m1 * e1) + (m2 * e2 + m3 * e3);
  }
  for (; i < e; ++i) {
    int n0 = adjsrc[i];
    float v0 = b2f(xb[(size_t)n0 * 64 + lane]);
    float m0 = fminf(v0 + 1e-7f, 80.f);
    float e0 = __expf(m0);
    den += e0;
    num += m0 * e0;
  }
  float res = fmaxf(h[(size_t)wid * 64 + lane], 0.f);
  outb[(size_t)wid * 64 + lane] = f2b(num / (den + 1e-16f) + res);
}

// ---------------- F=6 stats: shfl outer product (cheap) ----------------
__global__ __launch_bounds__(256) void k_ata6(const float* __restrict__ A,
                                              float* __restrict__ part) {
  constexpr int F = 6;
  int lane = threadIdx.x & 63;
  int w = __builtin_amdgcn_readfirstlane(threadIdx.x >> 6);
  bool act = lane < F;
  float Sloc[F];
#pragma unroll
  for (int c = 0; c < F; ++c) Sloc[c] = 0.f;
  float csloc = 0.f;
  int NW = gridDim.x * 4;
  for (int node = blockIdx.x * 4 + w; node < NN; node += NW) {
    float a = act ? A[(size_t)node * F + lane] : 0.f;
    csloc += a;
#pragma unroll
    for (int c = 0; c < F; ++c) {
      float ac = __shfl(a, c, 64);
      Sloc[c] += ac * a;
    }
  }
  __shared__ float ls[F * F + F];
  for (int idx = threadIdx.x; idx < F * F + F; idx += 256) ls[idx] = 0.f;
  __syncthreads();
  if (act) {
#pragma unroll
    for (int c = 0; c < F; ++c) atomicAdd(&ls[c * F + lane], Sloc[c]);
    atomicAdd(&ls[F * F + lane], csloc);
  }
  __syncthreads();
  float* dstp = part + (size_t)blockIdx.x * (F * F + F);
  for (int idx = threadIdx.x; idx < F * F + F; idx += 256) dstp[idx] = ls[idx];
}

// ---------------- F=64 stats: LDS-tiled rank-1 accumulation (bf16 input) -------
__global__ __launch_bounds__(256) void k_ata64(const unsigned short* __restrict__ Ab,
                                               float* __restrict__ part) {
  __shared__ float lA[64 * 64];   // [node][ch] (f32, converted at staging)
  __shared__ float lcs[64];
  int tid = threadIdx.x;
  int tx = tid & 15, ty = tid >> 4;
  float acc[4][4];
#pragma unroll
  for (int i = 0; i < 4; ++i)
#pragma unroll
    for (int j = 0; j < 4; ++j) acc[i][j] = 0.f;
  float cs0 = 0.f, cs1 = 0.f, cs2 = 0.f, cs3 = 0.f;
  if (tid < 64) lcs[tid] = 0.f;
  const uint2* A2 = (const uint2*)Ab;
  for (int tile = blockIdx.x; tile < NTILE; tile += gridDim.x) {
    int nbase = tile * 64;
    __syncthreads();   // protect lA from previous iteration's readers
#pragma unroll
    for (int k = 0; k < 4; ++k) {
      int node = ty + k * 16;
      int gn = nbase + node;
      float4 v;
      if (gn < NN) {
        uint2 u = A2[(size_t)gn * 16 + tx];
        v.x = b2f((unsigned short)(u.x & 0xffff));
        v.y = b2f((unsigned short)(u.x >> 16));
        v.z = b2f((unsigned short)(u.y & 0xffff));
        v.w = b2f((unsigned short)(u.y >> 16));
      } else {
        v = make_float4(0.f, 0.f, 0.f, 0.f);
      }
      *(float4*)&lA[node * 64 + tx * 4] = v;
      cs0 += v.x; cs1 += v.y; cs2 += v.z; cs3 += v.w;
    }
    __syncthreads();
#pragma unroll 4
    for (int node = 0; node < 64; ++node) {
      float4 rv = *(const float4*)&lA[node * 64 + ty * 4];
      float4 cv = *(const float4*)&lA[node * 64 + tx * 4];
      acc[0][0] += rv.x * cv.x; acc[0][1] += rv.x * cv.y;
      acc[0][2] += rv.x * cv.z; acc[0][3] += rv.x * cv.w;
      acc[1][0] += rv.y * cv.x; acc[1][1] += rv.y * cv.y;
      acc[1][2] += rv.y * cv.z; acc[1][3] += rv.y * cv.w;
      acc[2][0] += rv.z * cv.x; acc[2][1] += rv.z * cv.y;
      acc[2][2] += rv.z * cv.z; acc[2][3] += rv.z * cv.w;
      acc[3][0] += rv.w * cv.x; acc[3][1] += rv.w * cv.y;
      acc[3][2] += rv.w * cv.z; acc[3][3] += rv.w * cv.w;
    }
  }
  __syncthreads();
  atomicAdd(&lcs[tx * 4 + 0], cs0);
  atomicAdd(&lcs[tx * 4 + 1], cs1);
  atomicAdd(&lcs[tx * 4 + 2], cs2);
  atomicAdd(&lcs[tx * 4 + 3], cs3);
  float* dstp = part + (size_t)blockIdx.x * 4160;
#pragma unroll
  for (int i = 0; i < 4; ++i)
#pragma unroll
    for (int j = 0; j < 4; ++j)
      dstp[(ty * 4 + i) * 64 + tx * 4 + j] = acc[i][j];
  __syncthreads();
  if (tid < 64) dstp[4096 + tid] = lcs[tid];
}

// ---------------- reduce partials: block-per-index tree ----------------
__global__ void k_redB(const float* __restrict__ part, float* __restrict__ out,
                       int stride, int ngrid) {
  __shared__ float buf[256];
  int i = blockIdx.x;
  float s = 0.f;
  for (int g = threadIdx.x; g < ngrid; g += 256) s += part[(size_t)g * stride + i];
  buf[threadIdx.x] = s;
  __syncthreads();
  for (int off = 128; off; off >>= 1) {
    if (threadIdx.x < off) buf[threadIdx.x] += buf[threadIdx.x + off];
    __syncthreads();
  }
  if (threadIdx.x == 0) out[i] = buf[0];
}

// ---------------- BN params from covariance ----------------
template<int FIN, int FMID>
__global__ void k_bnprep(const float* __restrict__ S, const float* __restrict__ cs,
                         const float* __restrict__ Wm, const float* __restrict__ bm,
                         const float* __restrict__ gamma, const float* __restrict__ beta,
                         float* __restrict__ ab) {
  int j = blockIdx.x;
  int lane = threadIdx.x;
  bool act = (FIN == 64) || (lane < FIN);
  float wj = act ? Wm[lane * FMID + j] : 0.f;
  float mb = act ? cs[lane] * (1.f / NN) : 0.f;
  float t = mb * wj;
#pragma unroll
  for (int off = 32; off; off >>= 1) t += __shfl_xor(t, off, 64);
  float mulin = t;
  float acc = 0.f;
  for (int c = 0; c < FIN; ++c) {
    float sv = act ? S[c * FIN + lane] : 0.f;
    float p = sv * wj;
#pragma unroll
    for (int off = 32; off; off >>= 1) p += __shfl_xor(p, off, 64);
    acc += p * __shfl(wj, c, 64);
  }
  if (lane == 0) {
    float var = acc * (1.f / NN) - mulin * mulin;
    float rstd = rsqrtf(fmaxf(var, 0.f) + 1e-5f);
    float sc = rstd * gamma[j];
    ab[j] = sc;
    ab[FMID + j] = beta[j] - mulin * sc;
  }
}

// ---------------- layer-0 fused GEMM (VALU path, FIN=6) ----------------
template<int FIN, int FMID, int FOUT>
__global__ __launch_bounds__(256) void k_layer(const float* __restrict__ A,
                                               const float* __restrict__ Wm,
                                               const float* __restrict__ ab,
                                               const float* __restrict__ W2,
                                               const float* __restrict__ b2,
                                               float* __restrict__ H,
                                               unsigned short* __restrict__ XB) {
  constexpr int SM = FMID + 1;
  constexpr int MW = FMID / 4;
  constexpr int OW = FOUT / 4;
  __shared__ float lA[FIN * 65];
  __shared__ float lH_sep[64 * SM];
  int tid = threadIdx.x;
  int lane = tid & 63;
  int w = __builtin_amdgcn_readfirstlane(tid >> 6);
  int nbase = blockIdx.x * 64;
  for (int e = tid; e < 64 * FIN; e += 256) {
    int node = e / FIN, c = e - node * FIN;
    int gn = nbase + node;
    lA[c * 65 + node] = (gn < NN) ? A[(size_t)gn * FIN + c] : 0.f;
  }
  __syncthreads();
  float acc[MW];
#pragma unroll
  for (int j = 0; j < MW; ++j) acc[j] = 0.f;
#pragma unroll 4
  for (int c = 0; c < FIN; ++c) {
    float a = lA[c * 65 + lane];
#pragma unroll
    for (int j = 0; j < MW; ++j) acc[j] += a * Wm[c * FMID + w * MW + j];
  }
#pragma unroll
  for (int j = 0; j < MW; ++j) {
    float sc = ab[w * MW + j];
    float sh = ab[FMID + w * MW + j];
    lH_sep[lane * SM + w * MW + j] = fmaxf(acc[j] * sc + sh, 0.f);
  }
  __syncthreads();
  float acc2[OW];
#pragma unroll
  for (int j = 0; j < OW; ++j) acc2[j] = b2[w * OW + j];
#pragma unroll 4
  for (int c = 0; c < FMID; ++c) {
    float hv = lH_sep[lane * SM + c];
#pragma unroll
    for (int j = 0; j < OW; ++j) acc2[j] += hv * W2[c * FOUT + w * OW + j];
  }
  int node = nbase + lane;
  if (node < NN) {
    size_t base = (size_t)node * FOUT + w * OW;
#pragma unroll
    for (int j = 0; j < OW; ++j) {
      float hn = fmaxf(acc2[j], 0.f);
      H[base + j] = hn;
      XB[base + j] = f2b(hn);
    }
  }
}

// ---------------- weight pre-pack to MFMA fragment order (bf16) ----------------
__global__ void k_packW(const float* __restrict__ L_w1, const float* __restrict__ L_w2,
                        short* __restrict__ wmf, short* __restrict__ w2f) {
  int idx = blockIdx.x * 256 + threadIdx.x;
  if (idx >= 3 * 16384) return;
  int layer = idx / 16384;
  int r = idx - layer * 16384;
  bool isW2 = r >= 8192;
  int e = isW2 ? r - 8192 : r;
  int j = e & 7, lane = (e >> 3) & 63, t = e >> 9;
  int kgrp = lane >> 4, nlow = lane & 15;
  if (!isW2) {
    int nt = t >> 1, kc = t & 1;
    int k = kc * 32 + 8 * kgrp + j, n = nt * 16 + nlow;
    wmf[(size_t)layer * 8192 + e] = (short)f2b(L_w1[(size_t)layer * 64 * 128 + k * 128 + n]);
  } else {
    int nt = t >> 2, kc = t & 3;
    int k = kc * 32 + 8 * kgrp + j, n = nt * 16 + nlow;
    w2f[(size_t)layer * 8192 + e] = (short)f2b(L_w2[(size_t)layer * 128 * 64 + k * 64 + n]);
  }
}

// ---------------- MFMA fused layer (layers 1-3), bf16 A input ----------------
__global__ __launch_bounds__(256) void k_layerM(const unsigned short* __restrict__ Ab,
                                                const short* __restrict__ Wmf,
                                                const float* __restrict__ ab,
                                                const short* __restrict__ W2f,
                                                const float* __restrict__ b2,
                                                float* __restrict__ H,
                                                unsigned short* __restrict__ XB) {
  __shared__ short lFrag[8192];   // 16KB; GEMM1 a-frags then GEMM2 a-frags
  __shared__ float ls_ab[256];
  int tid = threadIdx.x;
  int lane = tid & 63;
  int w = tid >> 6;
  int nbase = blockIdx.x * 64;
  ls_ab[tid] = ab[tid];
#pragma unroll
  for (int it = 0; it < 2; ++it) {
    int e = tid + 256 * it;
    int ln = e & 63;
    int m = (e >> 6) & 3;
    int kc = e >> 8;
    int row = nbase + 16 * m + (ln & 15);
    int k0 = 32 * kc + 8 * (ln >> 4);
    short8 v;
    if (row < NN) {
      v = *(const short8*)&Ab[(size_t)row * 64 + k0];   // direct bf16 copy
    } else {
#pragma unroll
      for (int j = 0; j < 8; ++j) v[j] = 0;
    }
    *(short8*)&lFrag[((kc * 4 + m) * 64 + ln) * 8] = v;
  }
  __syncthreads();
  f32x4 acc[4][2];
#pragma unroll
  for (int m = 0; m < 4; ++m) {
    acc[m][0] = (f32x4){0.f, 0.f, 0.f, 0.f};
    acc[m][1] = (f32x4){0.f, 0.f, 0.f, 0.f};
  }
  short8 bf[2][2];
#pragma unroll
  for (int kc = 0; kc < 2; ++kc)
#pragma unroll
    for (int t = 0; t < 2; ++t) {
      int nt = 2 * w + t;
      bf[kc][t] = *(const short8*)&Wmf[(((nt * 2 + kc) * 64) + lane) * 8];
    }
#pragma unroll
  for (int kc = 0; kc < 2; ++kc)
#pragma unroll
    for (int m = 0; m < 4; ++m) {
      short8 af = *(short8*)&lFrag[((kc * 4 + m) * 64 + lane) * 8];
      acc[m][0] = __builtin_amdgcn_mfma_f32_16x16x32_bf16(af, bf[kc][0], acc[m][0], 0, 0, 0);
      acc[m][1] = __builtin_amdgcn_mfma_f32_16x16x32_bf16(af, bf[kc][1], acc[m][1], 0, 0, 0);
    }
  __syncthreads();
#pragma unroll
  for (int t = 0; t < 2; ++t) {
    int nt = 2 * w + t;
    int ch = 16 * nt + (lane & 15);
    float sc = ls_ab[ch];
    float sh = ls_ab[128 + ch];
    int kc2 = ch >> 5;
    int lgrp = (ch & 31) >> 3;
    int j2 = ch & 7;
#pragma unroll
    for (int m = 0; m < 4; ++m) {
#pragma unroll
      for (int r = 0; r < 4; ++r) {
        float mv = fmaxf(acc[m][t][r] * sc + sh, 0.f);
        int lp = lgrp * 16 + (lane >> 4) * 4 + r;
        lFrag[((kc2 * 4 + m) * 64 + lp) * 8 + j2] = (short)f2b(mv);
      }
    }
  }
  __syncthreads();
  float bias = b2[16 * w + (lane & 15)];
  f32x4 acc2[4];
#pragma unroll
  for (int m = 0; m < 4; ++m) acc2[m] = (f32x4){bias, bias, bias, bias};
#pragma unroll
  for (int kc = 0; kc < 4; ++kc) {
    short8 b2fr = *(const short8*)&W2f[(((w * 4 + kc) * 64) + lane) * 8];
#pragma unroll
    for (int m = 0; m < 4; ++m) {
      short8 af = *(short8*)&lFrag[((kc * 4 + m) * 64 + lane) * 8];
      acc2[m] = __builtin_amdgcn_mfma_f32_16x16x32_bf16(af, b2fr, acc2[m], 0, 0, 0);
    }
  }
  int colch = 16 * w + (lane & 15);
#pragma unroll
  for (int m = 0; m < 4; ++m) {
#pragma unroll
    for (int r = 0; r < 4; ++r) {
      int node = nbase + 16 * m + (lane >> 4) * 4 + r;
      if (node < NN) {
        size_t idx = (size_t)node * 64 + colch;
        float hn = H[idx] + acc2[m][r];
        H[idx] = hn;
        XB[idx] = f2b(fmaxf(hn, 0.f));
      }
    }
  }
}

// ---------------- pool: segmented register max (batch is sorted) ----------------
__global__ __launch_bounds__(256) void k_pool(const float* __restrict__ h,
                                              const int* __restrict__ batch,
                                              unsigned* __restrict__ gmax) {
  int wgid = blockIdx.x * 4 + (threadIdx.x >> 6);
  int lane = threadIdx.x & 63;
  const int per = (NN + POOL_WAVES - 1) / POOL_WAVES;  // 49
  int n0 = wgid * per;
  int n1 = min(n0 + per, NN);
  if (n0 >= NN) return;
  int g = batch[n0];
  float m = -INFINITY;
  for (int node = n0; node < n1; ++node) {
    int b = batch[node];
    if (b != g) {
      atomicMax(&gmax[(g << 6) + lane], fmap(m));
      m = -INFINITY;
      g = b;
    }
    m = fmaxf(m, h[(size_t)node * 64 + lane]);
  }
  atomicMax(&gmax[(g << 6) + lane], fmap(m));
}

__global__ void k_final(const unsigned* __restrict__ gmax, const float* __restrict__ w1,
                        const float* __restrict__ b1, const float* __restrict__ w2,
                        const float* __restrict__ b2, float* __restrict__ out) {
  int b = blockIdx.x;
  __shared__ float g[64], hid[64];
  int t = threadIdx.x;
  if (t < 64) {
    float v = funmap(gmax[b * 64 + t]);
    if (v == -INFINITY) v = 0.f;
    g[t] = v;
  }
  __syncthreads();
  if (t < 64) {
    float acc = b1[t];
    for (int c = 0; c < 64; ++c) acc += g[c] * w1[c * 64 + t];
    hid[t] = fmaxf(acc, 0.f);
  }
  __syncthreads();
  if (t < 80) {
    float acc = b2[t];
    for (int c = 0; c < 64; ++c) acc += hid[c] * w2[c * 80 + t];
    out[b * 80 + t] = acc;
  }
}

extern "C" void kernel_launch(void* const* d_in, const int* in_sizes, int n_in,
                              void* d_out, int out_size, void* d_ws, size_t ws_size,
                              hipStream_t stream) {
  const float* x       = (const float*)d_in[0];
  const int*   ei      = (const int*)d_in[1];
  const int*   batch   = (const int*)d_in[2];
  const float* cin_w1  = (const float*)d_in[3];
  const float* cin_b1  = (const float*)d_in[4];
  const float* cin_g1  = (const float*)d_in[5];
  const float* cin_be1 = (const float*)d_in[6];
  const float* cin_w2  = (const float*)d_in[7];
  const float* cin_b2  = (const float*)d_in[8];
  const float* L_w1    = (const float*)d_in[9];
  const float* L_b1    = (const float*)d_in[10];
  const float* L_g1    = (const float*)d_in[11];
  const float* L_be1   = (const float*)d_in[12];
  const float* L_w2    = (const float*)d_in[13];
  const float* L_b2    = (const float*)d_in[14];
  const float* mlp_w1  = (const float*)d_in[15];
  const float* mlp_b1  = (const float*)d_in[16];
  const float* mlp_w2  = (const float*)d_in[17];
  const float* mlp_b2  = (const float*)d_in[18];

  char* ws = (char*)d_ws;
  size_t off = 0;
  auto alloc = [&](size_t bytes) -> void* {
    void* p = ws + off;
    off = (off + bytes + 255) & ~(size_t)255;
    return p;
  };
  float*          A       = (float*)alloc((size_t)NN * 64 * 4);   // layer-0 f32 agg
  unsigned short* ab16    = (unsigned short*)alloc((size_t)NN * 64 * 2);  // layers 1-3 agg (bf16)
  float*          h       = (float*)alloc((size_t)NN * 64 * 4);
  unsigned short* xb      = (unsigned short*)alloc((size_t)NN * 64 * 2);
  int*            rowptr  = (int*)alloc((size_t)(NN + 1) * 4);
  int*            counts  = (int*)alloc((size_t)NN * 4);
  int*            counts8 = (int*)alloc((size_t)HCLS * NN * 4);
  int*            rank    = (int*)alloc((size_t)EE * 4);
  int*            adjsrc  = (int*)alloc((size_t)EE * 4);
  int*            partial = (int*)alloc(NSCAN * 4);
  int*            poffs   = (int*)alloc(128 * 4);
  short*          wmf     = (short*)alloc((size_t)3 * 8192 * 2);
  short*          w2f     = (short*)alloc((size_t)3 * 8192 * 2);
  float*          part    = (float*)alloc((size_t)AG6 * 4160 * 4);
  float*          Sfin    = (float*)alloc((size_t)4 * 4160 * 4);
  float*          ab      = (float*)alloc((size_t)4 * 256 * 4);
  unsigned*       gmax    = (unsigned*)alloc((size_t)BB * 64 * 4);
  (void)ws_size; (void)in_sizes; (void)n_in; (void)out_size;

  const int* srcp = ei;
  const int* dstp = ei + EE;

  // CSR build
  hipMemsetAsync(counts8, 0, (size_t)HCLS * NN * 4, stream);
  k_hist8<<<(EE + 255) / 256, 256, 0, stream>>>(dstp, counts8, rank);
  k_packW<<<192, 256, 0, stream>>>(L_w1, L_w2, wmf, w2f);
  k_off8<<<(NN + 255) / 256, 256, 0, stream>>>(counts8, counts);
  k_scan1<<<NSCAN, 1024, 0, stream>>>(counts, rowptr, partial);
  k_scan2<<<1, 128, 0, stream>>>(partial, poffs, gmax);
  k_scan3<<<NSCAN, 1024, 0, stream>>>(rowptr, poffs);
  k_place<<<(EE + 255) / 256, 256, 0, stream>>>(srcp, dstp, rank, rowptr, counts8, adjsrc);

  const int NB64 = (NN + 63) / 64;  // 1563

  // Layer 0: x[N,6] -> h[N,64] (+ xb = bf16 relu copy)
  {
    float* S = Sfin;
    float* cs = S + 6 * 6;
    float* ab0 = ab;
    k_agg0<<<NN / 4, 256, 0, stream>>>(x, rowptr, adjsrc, A);
    k_ata6<<<AG6, 256, 0, stream>>>(A, part);
    k_redB<<<42, 256, 0, stream>>>(part, S, 42, AG6);
    k_bnprep<6, 12><<<12, 64, 0, stream>>>(S, cs, cin_w1, cin_b1, cin_g1, cin_be1, ab0);
    k_layer<6, 12, 64><<<NB64, 256, 0, stream>>>(A, cin_w1, ab0, cin_w2, cin_b2, h, xb);
  }

  // Layers 1..3: h += MLP(BN(agg(relu(h)) @ W1)) @ W2  (MFMA path, bf16 A)
  for (int i = 0; i < 3; ++i) {
    float* S = Sfin + (size_t)(i + 1) * 4160;
    float* cs = S + 64 * 64;
    float* abi = ab + (size_t)(i + 1) * 256;
    k_aggb<<<NN / 4, 256, 0, stream>>>(xb, h, rowptr, adjsrc, ab16);
    k_ata64<<<AG64, 256, 0, stream>>>(ab16, part);
    k_redB<<<4160, 256, 0, stream>>>(part, S, 4160, AG64);
    k_bnprep<64, 128><<<128, 64, 0, stream>>>(S, cs, L_w1 + (size_t)i * 64 * 128,
                                              L_b1 + i * 128, L_g1 + i * 128,
                                              L_be1 + i * 128, abi);
    k_layerM<<<NB64, 256, 0, stream>>>(ab16, wmf + (size_t)i * 8192, abi,
                                       w2f + (size_t)i * 8192, L_b2 + i * 64, h, xb);
  }

  // Global max pool + final MLP
  k_pool<<<POOL_BLK, 256, 0, stream>>>(h, batch, gmax);
  k_final<<<BB, 128, 0, stream>>>(gmax, mlp_w1, mlp_b1, mlp_w2, mlp_b2, (float*)d_out);
}

// Round 18
// 525.840 us; speedup vs baseline: 1.1582x; 1.0429x over previous
//
#include <hip/hip_runtime.h>

#define NN 100000
#define EE 1600000
#define BB 64
#define NSCAN 98      // ceil(NN/1024)
#define AG6 1024      // grid for F=6 stats
#define AG64 640      // grid for F=64 tiled ata
#define NTILE 1563    // ceil(NN/64)
#define POOL_BLK 512
#define POOL_WAVES (POOL_BLK * 4)
#define HCLS 8        // hist classes (XCD-private count slices)

typedef float f32x4 __attribute__((ext_vector_type(4)));
typedef short short8 __attribute__((ext_vector_type(8)));

__device__ __forceinline__ unsigned fmap(float f) {
  unsigned u = __float_as_uint(f);
  return (u & 0x80000000u) ? ~u : (u | 0x80000000u);
}
__device__ __forceinline__ float funmap(unsigned m) {
  unsigned u = (m & 0x80000000u) ? (m ^ 0x80000000u) : ~m;
  return __uint_as_float(u);
}
__device__ __forceinline__ unsigned short f2b(float f) {
  unsigned u = __float_as_uint(f);
  unsigned r = (u + 0x7FFFu + ((u >> 16) & 1u)) >> 16;
  return (unsigned short)r;
}
__device__ __forceinline__ float b2f(unsigned short s) {
  return __uint_as_float(((unsigned)s) << 16);
}

// ---------------- CSR build (by dst) ----------------
__global__ void k_hist8(const int* __restrict__ dst, int* __restrict__ counts8,
                        int* __restrict__ rank) {
  int i = blockIdx.x * blockDim.x + threadIdx.x;
  int c = blockIdx.x & (HCLS - 1);
  if (i < EE) rank[i] = atomicAdd(&counts8[c * NN + dst[i]], 1);
}

// fused: per-node slice-exclusive offsets (in place) + block scan of totals
__global__ void k_scan1(int* __restrict__ counts8, int* __restrict__ rowptr,
                        int* __restrict__ partials) {
  __shared__ int buf[1024];
  int i = blockIdx.x * 1024 + threadIdx.x;
  int v = 0;
  if (i < NN) {
    int t = 0;
#pragma unroll
    for (int c = 0; c < HCLS; ++c) {
      int x = counts8[c * NN + i];
      counts8[c * NN + i] = t;
      t += x;
    }
    v = t;
  }
  buf[threadIdx.x] = v;
  __syncthreads();
  for (int off = 1; off < 1024; off <<= 1) {
    int t = (threadIdx.x >= off) ? buf[threadIdx.x - off] : 0;
    __syncthreads();
    buf[threadIdx.x] += t;
    __syncthreads();
  }
  int incl = buf[threadIdx.x];
  if (i < NN) rowptr[i] = incl - v;
  if (threadIdx.x == 1023) partials[blockIdx.x] = incl;
}

__global__ void k_scan2(const int* __restrict__ partials, int* __restrict__ poffs,
                        unsigned* __restrict__ gmax) {
  __shared__ int buf[128];
  int t = threadIdx.x;
  int v = (t < NSCAN) ? partials[t] : 0;
  buf[t] = v;
  __syncthreads();
  for (int off = 1; off < 128; off <<= 1) {
    int u = (t >= off) ? buf[t - off] : 0;
    __syncthreads();
    buf[t] += u;
    __syncthreads();
  }
  poffs[t] = buf[t] - v;
  for (int i = t; i < BB * 64; i += 128) gmax[i] = 0x007FFFFFu;  // fmap(-inf)
}

__global__ void k_scan3(int* __restrict__ rowptr, const int* __restrict__ poffs) {
  int i = blockIdx.x * 1024 + threadIdx.x;
  if (i < NN) rowptr[i] += poffs[blockIdx.x];
  if (i == 0) rowptr[NN] = EE;
}

__global__ __launch_bounds__(256) void k_place(const int* __restrict__ src,
                                               const int* __restrict__ dst,
                                               const int* __restrict__ rank,
                                               const int* __restrict__ rowptr,
                                               const int* __restrict__ counts8,
                                               int* __restrict__ adjsrc) {
  int i = blockIdx.x * blockDim.x + threadIdx.x;
  if (i < EE) {
    int c = (i >> 8) & (HCLS - 1);
    int d = dst[i];
    adjsrc[rowptr[d] + counts8[c * NN + d] + rank[i]] = src[i];
  }
}

// ---------------- layer-0 aggregation: 8-edge-parallel, F=6 ----------------
__global__ __launch_bounds__(256) void k_agg0(const float* __restrict__ xin,
                                              const int* __restrict__ rowptr,
                                              const int* __restrict__ adjsrc,
                                              float* __restrict__ out) {
  int w = __builtin_amdgcn_readfirstlane(threadIdx.x >> 6);
  int lane = threadIdx.x & 63;
  int wid = blockIdx.x * 4 + w;
  if (wid >= NN) return;
  int eslot = lane >> 3;   // 0..7
  int ch = lane & 7;       // 0..7, <6 active
  bool act = ch < 6;
  int s = rowptr[wid], e = rowptr[wid + 1];
  float den = 0.f, num = 0.f;
  for (int base = s; base < e; base += 8) {
    int ei = base + eslot;
    bool valid = ei < e;
    int n0 = adjsrc[valid ? ei : s];
    float v = act ? xin[(size_t)n0 * 6 + ch] : 0.f;
    float m = fminf(fmaxf(v, 0.f) + 1e-7f, 80.f);
    float ex = valid ? __expf(m) : 0.f;
    den += ex;
    num += m * ex;
  }
#pragma unroll
  for (int off = 8; off < 64; off <<= 1) {
    den += __shfl_xor(den, off, 64);
    num += __shfl_xor(num, off, 64);
  }
  if (eslot == 0 && act) {
    float xr = xin[(size_t)wid * 6 + ch];
    out[(size_t)wid * 6 + ch] = num / (den + 1e-16f) + xr;
  }
}

// ---------------- layers 1-3 aggregation: bf16 gather, 8-deep unroll ----------
__global__ __launch_bounds__(256) void k_aggb(const unsigned short* __restrict__ xb,
                                              const float* __restrict__ h,
                                              const int* __restrict__ rowptr,
                                              const int* __restrict__ adjsrc,
                                              unsigned short* __restrict__ outb) {
  int w = __builtin_amdgcn_readfirstlane(threadIdx.x >> 6);
  int lane = threadIdx.x & 63;
  int wid = blockIdx.x * 4 + w;
  if (wid >= NN) return;
  int s = rowptr[wid], e = rowptr[wid + 1];
  float den = 0.f, num = 0.f;
  int i = s;
  for (; i + 7 < e; i += 8) {
    int n[8];
#pragma unroll
    for (int k = 0; k < 8; ++k) n[k] = adjsrc[i + k];
    float m[8];
#pragma unroll
    for (int k = 0; k < 8; ++k)
      m[k] = fminf(b2f(xb[(size_t)n[k] * 64 + lane]) + 1e-7f, 80.f);
#pragma unroll
    for (int k = 0; k < 8; ++k) {
      float ex = __expf(m[k]);
      den += ex;
      num += m[k] * ex;
    }
  }
  for (; i + 3 < e; i += 4) {
    int n0 = adjsrc[i], n1 = adjsrc[i + 1], n2 = adjsrc[i + 2], n3 = adjsrc[i + 3];
    float m0 = fminf(b2f(xb[(size_t)n0 * 64 + lane]) + 1e-7f, 80.f);
    float m1 = fminf(b2f(xb[(size_t)n1 * 64 + lane]) + 1e-7f, 80.f);
    float m2 = fminf(b2f(xb[(size_t)n2 * 64 + lane]) + 1e-7f, 80.f);
    float m3 = fminf(b2f(xb[(size_t)n3 * 64 + lane]) + 1e-7f, 80.f);
    float e0 = __expf(m0), e1 = __expf(m1), e2 = __expf(m2), e3 = __expf(m3);
    den += (e0 + e1) + (e2 + e3);
    num += (m0 * e0 + m1 * e1) + (m2 * e2 + m3 * e3);
  }
  for (; i < e; ++i) {
    int n0 = adjsrc[i];
    float m0 = fminf(b2f(xb[(size_t)n0 * 64 + lane]) + 1e-7f, 80.f);
    float e0 = __expf(m0);
    den += e0;
    num += m0 * e0;
  }
  float res = fmaxf(h[(size_t)wid * 64 + lane], 0.f);
  outb[(size_t)wid * 64 + lane] = f2b(num / (den + 1e-16f) + res);
}

// ---------------- F=6 stats: shfl outer product (cheap) ----------------
__global__ __launch_bounds__(256) void k_ata6(const float* __restrict__ A,
                                              float* __restrict__ part) {
  constexpr int F = 6;
  int lane = threadIdx.x & 63;
  int w = __builtin_amdgcn_readfirstlane(threadIdx.x >> 6);
  bool act = lane < F;
  float Sloc[F];
#pragma unroll
  for (int c = 0; c < F; ++c) Sloc[c] = 0.f;
  float csloc = 0.f;
  int NW = gridDim.x * 4;
  for (int node = blockIdx.x * 4 + w; node < NN; node += NW) {
    float a = act ? A[(size_t)node * F + lane] : 0.f;
    csloc += a;
#pragma unroll
    for (int c = 0; c < F; ++c) {
      float ac = __shfl(a, c, 64);
      Sloc[c] += ac * a;
    }
  }
  __shared__ float ls[F * F + F];
  for (int idx = threadIdx.x; idx < F * F + F; idx += 256) ls[idx] = 0.f;
  __syncthreads();
  if (act) {
#pragma unroll
    for (int c = 0; c < F; ++c) atomicAdd(&ls[c * F + lane], Sloc[c]);
    atomicAdd(&ls[F * F + lane], csloc);
  }
  __syncthreads();
  float* dstp = part + (size_t)blockIdx.x * (F * F + F);
  for (int idx = threadIdx.x; idx < F * F + F; idx += 256) dstp[idx] = ls[idx];
}

// ---------------- F=64 stats: LDS-tiled rank-1 accumulation (bf16 input) -------
__global__ __launch_bounds__(256) void k_ata64(const unsigned short* __restrict__ Ab,
                                               float* __restrict__ part) {
  __shared__ float lA[64 * 64];   // [node][ch] (f32, converted at staging)
  __shared__ float lcs[64];
  int tid = threadIdx.x;
  int tx = tid & 15, ty = tid >> 4;
  float acc[4][4];
#pragma unroll
  for (int i = 0; i < 4; ++i)
#pragma unroll
    for (int j = 0; j < 4; ++j) acc[i][j] = 0.f;
  float cs0 = 0.f, cs1 = 0.f, cs2 = 0.f, cs3 = 0.f;
  if (tid < 64) lcs[tid] = 0.f;
  const uint2* A2 = (const uint2*)Ab;
  for (int tile = blockIdx.x; tile < NTILE; tile += gridDim.x) {
    int nbase = tile * 64;
    __syncthreads();   // protect lA from previous iteration's readers
#pragma unroll
    for (int k = 0; k < 4; ++k) {
      int node = ty + k * 16;
      int gn = nbase + node;
      float4 v;
      if (gn < NN) {
        uint2 u = A2[(size_t)gn * 16 + tx];
        v.x = b2f((unsigned short)(u.x & 0xffff));
        v.y = b2f((unsigned short)(u.x >> 16));
        v.z = b2f((unsigned short)(u.y & 0xffff));
        v.w = b2f((unsigned short)(u.y >> 16));
      } else {
        v = make_float4(0.f, 0.f, 0.f, 0.f);
      }
      *(float4*)&lA[node * 64 + tx * 4] = v;
      cs0 += v.x; cs1 += v.y; cs2 += v.z; cs3 += v.w;
    }
    __syncthreads();
#pragma unroll 4
    for (int node = 0; node < 64; ++node) {
      float4 rv = *(const float4*)&lA[node * 64 + ty * 4];
      float4 cv = *(const float4*)&lA[node * 64 + tx * 4];
      acc[0][0] += rv.x * cv.x; acc[0][1] += rv.x * cv.y;
      acc[0][2] += rv.x * cv.z; acc[0][3] += rv.x * cv.w;
      acc[1][0] += rv.y * cv.x; acc[1][1] += rv.y * cv.y;
      acc[1][2] += rv.y * cv.z; acc[1][3] += rv.y * cv.w;
      acc[2][0] += rv.z * cv.x; acc[2][1] += rv.z * cv.y;
      acc[2][2] += rv.z * cv.z; acc[2][3] += rv.z * cv.w;
      acc[3][0] += rv.w * cv.x; acc[3][1] += rv.w * cv.y;
      acc[3][2] += rv.w * cv.z; acc[3][3] += rv.w * cv.w;
    }
  }
  __syncthreads();
  atomicAdd(&lcs[tx * 4 + 0], cs0);
  atomicAdd(&lcs[tx * 4 + 1], cs1);
  atomicAdd(&lcs[tx * 4 + 2], cs2);
  atomicAdd(&lcs[tx * 4 + 3], cs3);
  float* dstp = part + (size_t)blockIdx.x * 4160;
#pragma unroll
  for (int i = 0; i < 4; ++i)
#pragma unroll
    for (int j = 0; j < 4; ++j)
      dstp[(ty * 4 + i) * 64 + tx * 4 + j] = acc[i][j];
  __syncthreads();
  if (tid < 64) dstp[4096 + tid] = lcs[tid];
}

// ---------------- reduce partials: block-per-index tree ----------------
__global__ void k_redB(const float* __restrict__ part, float* __restrict__ out,
                       int stride, int ngrid) {
  __shared__ float buf[256];
  int i = blockIdx.x;
  float s = 0.f;
  for (int g = threadIdx.x; g < ngrid; g += 256) s += part[(size_t)g * stride + i];
  buf[threadIdx.x] = s;
  __syncthreads();
  for (int off = 128; off; off >>= 1) {
    if (threadIdx.x < off) buf[threadIdx.x] += buf[threadIdx.x + off];
    __syncthreads();
  }
  if (threadIdx.x == 0) out[i] = buf[0];
}

// ---------------- BN params from covariance ----------------
template<int FIN, int FMID>
__global__ void k_bnprep(const float* __restrict__ S, const float* __restrict__ cs,
                         const float* __restrict__ Wm, const float* __restrict__ bm,
                         const float* __restrict__ gamma, const float* __restrict__ beta,
                         float* __restrict__ ab) {
  int j = blockIdx.x;
  int lane = threadIdx.x;
  bool act = (FIN == 64) || (lane < FIN);
  float wj = act ? Wm[lane * FMID + j] : 0.f;
  float mb = act ? cs[lane] * (1.f / NN) : 0.f;
  float t = mb * wj;
#pragma unroll
  for (int off = 32; off; off >>= 1) t += __shfl_xor(t, off, 64);
  float mulin = t;
  float acc = 0.f;
  for (int c = 0; c < FIN; ++c) {
    float sv = act ? S[c * FIN + lane] : 0.f;
    float p = sv * wj;
#pragma unroll
    for (int off = 32; off; off >>= 1) p += __shfl_xor(p, off, 64);
    acc += p * __shfl(wj, c, 64);
  }
  if (lane == 0) {
    float var = acc * (1.f / NN) - mulin * mulin;
    float rstd = rsqrtf(fmaxf(var, 0.f) + 1e-5f);
    float sc = rstd * gamma[j];
    ab[j] = sc;
    ab[FMID + j] = beta[j] - mulin * sc;
  }
}

// ---------------- layer-0 fused GEMM (VALU path, FIN=6) ----------------
template<int FIN, int FMID, int FOUT>
__global__ __launch_bounds__(256) void k_layer(const float* __restrict__ A,
                                               const float* __restrict__ Wm,
                                               const float* __restrict__ ab,
                                               const float* __restrict__ W2,
                                               const float* __restrict__ b2,
                                               float* __restrict__ H,
                                               unsigned short* __restrict__ XB) {
  constexpr int SM = FMID + 1;
  constexpr int MW = FMID / 4;
  constexpr int OW = FOUT / 4;
  __shared__ float lA[FIN * 65];
  __shared__ float lH_sep[64 * SM];
  int tid = threadIdx.x;
  int lane = tid & 63;
  int w = __builtin_amdgcn_readfirstlane(tid >> 6);
  int nbase = blockIdx.x * 64;
  for (int e = tid; e < 64 * FIN; e += 256) {
    int node = e / FIN, c = e - node * FIN;
    int gn = nbase + node;
    lA[c * 65 + node] = (gn < NN) ? A[(size_t)gn * FIN + c] : 0.f;
  }
  __syncthreads();
  float acc[MW];
#pragma unroll
  for (int j = 0; j < MW; ++j) acc[j] = 0.f;
#pragma unroll 4
  for (int c = 0; c < FIN; ++c) {
    float a = lA[c * 65 + lane];
#pragma unroll
    for (int j = 0; j < MW; ++j) acc[j] += a * Wm[c * FMID + w * MW + j];
  }
#pragma unroll
  for (int j = 0; j < MW; ++j) {
    float sc = ab[w * MW + j];
    float sh = ab[FMID + w * MW + j];
    lH_sep[lane * SM + w * MW + j] = fmaxf(acc[j] * sc + sh, 0.f);
  }
  __syncthreads();
  float acc2[OW];
#pragma unroll
  for (int j = 0; j < OW; ++j) acc2[j] = b2[w * OW + j];
#pragma unroll 4
  for (int c = 0; c < FMID; ++c) {
    float hv = lH_sep[lane * SM + c];
#pragma unroll
    for (int j = 0; j < OW; ++j) acc2[j] += hv * W2[c * FOUT + w * OW + j];
  }
  int node = nbase + lane;
  if (node < NN) {
    size_t base = (size_t)node * FOUT + w * OW;
#pragma unroll
    for (int j = 0; j < OW; ++j) {
      float hn = fmaxf(acc2[j], 0.f);
      H[base + j] = hn;
      XB[base + j] = f2b(hn);
    }
  }
}

// ---------------- weight pre-pack to MFMA fragment order (bf16) ----------------
__global__ void k_packW(const float* __restrict__ L_w1, const float* __restrict__ L_w2,
                        short* __restrict__ wmf, short* __restrict__ w2f) {
  int idx = blockIdx.x * 256 + threadIdx.x;
  if (idx >= 3 * 16384) return;
  int layer = idx / 16384;
  int r = idx - layer * 16384;
  bool isW2 = r >= 8192;
  int e = isW2 ? r - 8192 : r;
  int j = e & 7, lane = (e >> 3) & 63, t = e >> 9;
  int kgrp = lane >> 4, nlow = lane & 15;
  if (!isW2) {
    int nt = t >> 1, kc = t & 1;
    int k = kc * 32 + 8 * kgrp + j, n = nt * 16 + nlow;
    wmf[(size_t)layer * 8192 + e] = (short)f2b(L_w1[(size_t)layer * 64 * 128 + k * 128 + n]);
  } else {
    int nt = t >> 2, kc = t & 3;
    int k = kc * 32 + 8 * kgrp + j, n = nt * 16 + nlow;
    w2f[(size_t)layer * 8192 + e] = (short)f2b(L_w2[(size_t)layer * 128 * 64 + k * 64 + n]);
  }
}

// ---------------- MFMA fused layer (layers 1-3), bf16 A input ----------------
__global__ __launch_bounds__(256) void k_layerM(const unsigned short* __restrict__ Ab,
                                                const short* __restrict__ Wmf,
                                                const float* __restrict__ ab,
                                                const short* __restrict__ W2f,
                                                const float* __restrict__ b2,
                                                float* __restrict__ H,
                                                unsigned short* __restrict__ XB) {
  __shared__ short lFrag[8192];   // 16KB; GEMM1 a-frags then GEMM2 a-frags
  __shared__ float ls_ab[256];
  int tid = threadIdx.x;
  int lane = tid & 63;
  int w = tid >> 6;
  int nbase = blockIdx.x * 64;
  ls_ab[tid] = ab[tid];
#pragma unroll
  for (int it = 0; it < 2; ++it) {
    int e = tid + 256 * it;
    int ln = e & 63;
    int m = (e >> 6) & 3;
    int kc = e >> 8;
    int row = nbase + 16 * m + (ln & 15);
    int k0 = 32 * kc + 8 * (ln >> 4);
    short8 v;
    if (row < NN) {
      v = *(const short8*)&Ab[(size_t)row * 64 + k0];   // direct bf16 copy
    } else {
#pragma unroll
      for (int j = 0; j < 8; ++j) v[j] = 0;
    }
    *(short8*)&lFrag[((kc * 4 + m) * 64 + ln) * 8] = v;
  }
  __syncthreads();
  f32x4 acc[4][2];
#pragma unroll
  for (int m = 0; m < 4; ++m) {
    acc[m][0] = (f32x4){0.f, 0.f, 0.f, 0.f};
    acc[m][1] = (f32x4){0.f, 0.f, 0.f, 0.f};
  }
  short8 bf[2][2];
#pragma unroll
  for (int kc = 0; kc < 2; ++kc)
#pragma unroll
    for (int t = 0; t < 2; ++t) {
      int nt = 2 * w + t;
      bf[kc][t] = *(const short8*)&Wmf[(((nt * 2 + kc) * 64) + lane) * 8];
    }
#pragma unroll
  for (int kc = 0; kc < 2; ++kc)
#pragma unroll
    for (int m = 0; m < 4; ++m) {
      short8 af = *(short8*)&lFrag[((kc * 4 + m) * 64 + lane) * 8];
      acc[m][0] = __builtin_amdgcn_mfma_f32_16x16x32_bf16(af, bf[kc][0], acc[m][0], 0, 0, 0);
      acc[m][1] = __builtin_amdgcn_mfma_f32_16x16x32_bf16(af, bf[kc][1], acc[m][1], 0, 0, 0);
    }
  __syncthreads();
#pragma unroll
  for (int t = 0; t < 2; ++t) {
    int nt = 2 * w + t;
    int ch = 16 * nt + (lane & 15);
    float sc = ls_ab[ch];
    float sh = ls_ab[128 + ch];
    int kc2 = ch >> 5;
    int lgrp = (ch & 31) >> 3;
    int j2 = ch & 7;
#pragma unroll
    for (int m = 0; m < 4; ++m) {
#pragma unroll
      for (int r = 0; r < 4; ++r) {
        float mv = fmaxf(acc[m][t][r] * sc + sh, 0.f);
        int lp = lgrp * 16 + (lane >> 4) * 4 + r;
        lFrag[((kc2 * 4 + m) * 64 + lp) * 8 + j2] = (short)f2b(mv);
      }
    }
  }
  __syncthreads();
  float bias = b2[16 * w + (lane & 15)];
  f32x4 acc2[4];
#pragma unroll
  for (int m = 0; m < 4; ++m) acc2[m] = (f32x4){bias, bias, bias, bias};
#pragma unroll
  for (int kc = 0; kc < 4; ++kc) {
    short8 b2fr = *(const short8*)&W2f[(((w * 4 + kc) * 64) + lane) * 8];
#pragma unroll
    for (int m = 0; m < 4; ++m) {
      short8 af = *(short8*)&lFrag[((kc * 4 + m) * 64 + lane) * 8];
      acc2[m] = __builtin_amdgcn_mfma_f32_16x16x32_bf16(af, b2fr, acc2[m], 0, 0, 0);
    }
  }
  int colch = 16 * w + (lane & 15);
#pragma unroll
  for (int m = 0; m < 4; ++m) {
#pragma unroll
    for (int r = 0; r < 4; ++r) {
      int node = nbase + 16 * m + (lane >> 4) * 4 + r;
      if (node < NN) {
        size_t idx = (size_t)node * 64 + colch;
        float hn = H[idx] + acc2[m][r];
        H[idx] = hn;
        XB[idx] = f2b(fmaxf(hn, 0.f));
      }
    }
  }
}

// ---------------- pool: segmented register max (batch is sorted) ----------------
__global__ __launch_bounds__(256) void k_pool(const float* __restrict__ h,
                                              const int* __restrict__ batch,
                                              unsigned* __restrict__ gmax) {
  int wgid = blockIdx.x * 4 + (threadIdx.x >> 6);
  int lane = threadIdx.x & 63;
  const int per = (NN + POOL_WAVES - 1) / POOL_WAVES;  // 49
  int n0 = wgid * per;
  int n1 = min(n0 + per, NN);
  if (n0 >= NN) return;
  int g = batch[n0];
  float m = -INFINITY;
  for (int node = n0; node < n1; ++node) {
    int b = batch[node];
    if (b != g) {
      atomicMax(&gmax[(g << 6) + lane], fmap(m));
      m = -INFINITY;
      g = b;
    }
    m = fmaxf(m, h[(size_t)node * 64 + lane]);
  }
  atomicMax(&gmax[(g << 6) + lane], fmap(m));
}

__global__ void k_final(const unsigned* __restrict__ gmax, const float* __restrict__ w1,
                        const float* __restrict__ b1, const float* __restrict__ w2,
                        const float* __restrict__ b2, float* __restrict__ out) {
  int b = blockIdx.x;
  __shared__ float g[64], hid[64];
  int t = threadIdx.x;
  if (t < 64) {
    float v = funmap(gmax[b * 64 + t]);
    if (v == -INFINITY) v = 0.f;
    g[t] = v;
  }
  __syncthreads();
  if (t < 64) {
    float acc = b1[t];
    for (int c = 0; c < 64; ++c) acc += g[c] * w1[c * 64 + t];
    hid[t] = fmaxf(acc, 0.f);
  }
  __syncthreads();
  if (t < 80) {
    float acc = b2[t];
    for (int c = 0; c < 64; ++c) acc += hid[c] * w2[c * 80 + t];
    out[b * 80 + t] = acc;
  }
}

extern "C" void kernel_launch(void* const* d_in, const int* in_sizes, int n_in,
                              void* d_out, int out_size, void* d_ws, size_t ws_size,
                              hipStream_t stream) {
  const float* x       = (const float*)d_in[0];
  const int*   ei      = (const int*)d_in[1];
  const int*   batch   = (const int*)d_in[2];
  const float* cin_w1  = (const float*)d_in[3];
  const float* cin_b1  = (const float*)d_in[4];
  const float* cin_g1  = (const float*)d_in[5];
  const float* cin_be1 = (const float*)d_in[6];
  const float* cin_w2  = (const float*)d_in[7];
  const float* cin_b2  = (const float*)d_in[8];
  const float* L_w1    = (const float*)d_in[9];
  const float* L_b1    = (const float*)d_in[10];
  const float* L_g1    = (const float*)d_in[11];
  const float* L_be1   = (const float*)d_in[12];
  const float* L_w2    = (const float*)d_in[13];
  const float* L_b2    = (const float*)d_in[14];
  const float* mlp_w1  = (const float*)d_in[15];
  const float* mlp_b1  = (const float*)d_in[16];
  const float* mlp_w2  = (const float*)d_in[17];
  const float* mlp_b2  = (const float*)d_in[18];

  char* ws = (char*)d_ws;
  size_t off = 0;
  auto alloc = [&](size_t bytes) -> void* {
    void* p = ws + off;
    off = (off + bytes + 255) & ~(size_t)255;
    return p;
  };
  float*          A       = (float*)alloc((size_t)NN * 64 * 4);   // layer-0 f32 agg
  unsigned short* ab16    = (unsigned short*)alloc((size_t)NN * 64 * 2);  // layers 1-3 agg (bf16)
  float*          h       = (float*)alloc((size_t)NN * 64 * 4);
  unsigned short* xb      = (unsigned short*)alloc((size_t)NN * 64 * 2);
  int*            rowptr  = (int*)alloc((size_t)(NN + 1) * 4);
  int*            counts8 = (int*)alloc((size_t)HCLS * NN * 4);
  int*            rank    = (int*)alloc((size_t)EE * 4);
  int*            adjsrc  = (int*)alloc((size_t)EE * 4);
  int*            partial = (int*)alloc(NSCAN * 4);
  int*            poffs   = (int*)alloc(128 * 4);
  short*          wmf     = (short*)alloc((size_t)3 * 8192 * 2);
  short*          w2f     = (short*)alloc((size_t)3 * 8192 * 2);
  float*          part    = (float*)alloc((size_t)AG6 * 4160 * 4);
  float*          Sfin    = (float*)alloc((size_t)4 * 4160 * 4);
  float*          ab      = (float*)alloc((size_t)4 * 256 * 4);
  unsigned*       gmax    = (unsigned*)alloc((size_t)BB * 64 * 4);
  (void)ws_size; (void)in_sizes; (void)n_in; (void)out_size;

  const int* srcp = ei;
  const int* dstp = ei + EE;

  // CSR build
  hipMemsetAsync(counts8, 0, (size_t)HCLS * NN * 4, stream);
  k_hist8<<<(EE + 255) / 256, 256, 0, stream>>>(dstp, counts8, rank);
  k_packW<<<192, 256, 0, stream>>>(L_w1, L_w2, wmf, w2f);
  k_scan1<<<NSCAN, 1024, 0, stream>>>(counts8, rowptr, partial);
  k_scan2<<<1, 128, 0, stream>>>(partial, poffs, gmax);
  k_scan3<<<NSCAN, 1024, 0, stream>>>(rowptr, poffs);
  k_place<<<(EE + 255) / 256, 256, 0, stream>>>(srcp, dstp, rank, rowptr, counts8, adjsrc);

  const int NB64 = (NN + 63) / 64;  // 1563

  // Layer 0: x[N,6] -> h[N,64] (+ xb = bf16 relu copy)
  {
    float* S = Sfin;
    float* cs = S + 6 * 6;
    float* ab0 = ab;
    k_agg0<<<NN / 4, 256, 0, stream>>>(x, rowptr, adjsrc, A);
    k_ata6<<<AG6, 256, 0, stream>>>(A, part);
    k_redB<<<42, 256, 0, stream>>>(part, S, 42, AG6);
    k_bnprep<6, 12><<<12, 64, 0, stream>>>(S, cs, cin_w1, cin_b1, cin_g1, cin_be1, ab0);
    k_layer<6, 12, 64><<<NB64, 256, 0, stream>>>(A, cin_w1, ab0, cin_w2, cin_b2, h, xb);
  }

  // Layers 1..3: h += MLP(BN(agg(relu(h)) @ W1)) @ W2  (MFMA path, bf16 A)
  for (int i = 0; i < 3; ++i) {
    float* S = Sfin + (size_t)(i + 1) * 4160;
    float* cs = S + 64 * 64;
    float* abi = ab + (size_t)(i + 1) * 256;
    k_aggb<<<NN / 4, 256, 0, stream>>>(xb, h, rowptr, adjsrc, ab16);
    k_ata64<<<AG64, 256, 0, stream>>>(ab16, part);
    k_redB<<<4160, 256, 0, stream>>>(part, S, 4160, AG64);
    k_bnprep<64, 128><<<128, 64, 0, stream>>>(S, cs, L_w1 + (size_t)i * 64 * 128,
                                              L_b1 + i * 128, L_g1 + i * 128,
                                              L_be1 + i * 128, abi);
    k_layerM<<<NB64, 256, 0, stream>>>(ab16, wmf + (size_t)i * 8192, abi,
                                       w2f + (size_t)i * 8192, L_b2 + i * 64, h, xb);
  }

  // Global max pool + final MLP
  k_pool<<<POOL_BLK, 256, 0, stream>>>(h, batch, gmax);
  k_final<<<BB, 128, 0, stream>>>(gmax, mlp_w1, mlp_b1, mlp_w2, mlp_b2, (float*)d_out);
}